// Round 7
// baseline (8816.038 us; speedup 1.0000x reference)
//
#include <hip/hip_runtime.h>

#define DI __device__ __forceinline__

constexpr int B = 32, L = 100, T = 50;
constexpr int VS = 20000;
constexpr int HR = 250, HD = 500;
constexpr int INE = 460;
constexpr int OC = 1072;   // padded Wcat columns: 500 hwd | 60 hz | 500 hWo1 | 1 hwl | pad
constexpr int NB = 63;     // blocks in recurrent kernels

// ---- workspace byte offsets ----
constexpr size_t O_X      = 0;                      // x [B][L][460] f32
constexpr size_t O_SX     = 5888000;                // sent_x [T][B][400] f32
constexpr size_t O_WIHFT  = 8448000;                // enc_Wih_f^T [460][1000] f32
constexpr size_t O_WIHBT  = 10288000;
constexpr size_t O_WDECT  = 12128000;               // dec_Wih^T [400][2000] f32
constexpr size_t O_W4ENC  = 15328000;               // [2dir][250u][250k][4g] f32
constexpr size_t O_W4DEC  = 17328000;               // [500u][500k][4g] f32
constexpr size_t O_WCAT   = 21328000;               // [500][1072] f32
constexpr size_t O_XWF    = 23472000;               // [100][1000][32] f64
constexpr size_t O_XWB    = 49072000;
constexpr size_t O_XWD    = 74672000;               // [50][2000][32] f64
constexpr size_t O_EOB    = 100272000;              // enc_out [32][100][500] f64
constexpr size_t O_E2     = 113072000;              // [32][100][500] f64
constexpr size_t O_PROJ   = 125872000;              // [50][32][1072] f64
constexpr size_t O_HD     = 139593600;              // [1600][500] f64 (row t*32+b)
constexpr size_t O_HGENC  = 145993600;              // [2ph][16000] f64
constexpr size_t O_HGDEC  = 146249600;              // [2ph][16000] f64
constexpr size_t O_HENCF  = 146505600;              // [2dir][250][32] f64 final
constexpr size_t O_CENCF  = 146633600;
constexpr size_t O_CDEC0  = 146761600;              // [500][32] f64 scrambled c init
constexpr size_t O_HDECF  = 146889600;              // [500][32] f64 final
constexpr size_t O_CDECF  = 147017600;
constexpr size_t O_AD     = 147145600;              // a f64 [1600][100]
constexpr size_t O_ATTN   = 148425600;              // [32][50][100] f32
constexpr size_t O_EWL    = 149065600;              // [32][100] f64
constexpr size_t O_SXL    = 149091200;              // [1600] f64 (t*32+b)
constexpr size_t O_AWL    = 149104000;              // [1600] f64 (b*50+t)
constexpr size_t O_LAM    = 149116800;              // [1600] f32
constexpr size_t O_LS1    = 149123200;              // [1600] f32
constexpr size_t O_WIDX   = 149129600;              // [1600] int
constexpr size_t O_BAR    = 149136000;              // 2 x 64 slots x 16 ints (64B padded)
constexpr size_t O_OUTS   = 149144192;              // outs f32 [1600][512]
// end ~152.4 MB (<=158.4MB proven)

// output element offsets (f32)
constexpr size_t OUT_HT  = 32000000;
constexpr size_t OUT_CT  = 32016000;
constexpr size_t OUT_AP  = 32032000;
constexpr size_t OUT_DP  = 32512000;

DI double dsig(double x) { return 1.0 / (1.0 + exp(-x)); }

// distributed-slot device barrier: each block signals its own 64B slot (parallel RMWs),
// wave0 lanes poll one slot each. Release: threadfence before exch. Acquire: threadfence after.
DI void gbar(int* slots, int target) {
    __syncthreads();
    if (threadIdx.x == 0) {
        __threadfence();                                     // release: flush this block's stores
        atomicExch(&slots[blockIdx.x * 16], target);         // RMW -> coherence point, own line
    }
    if (threadIdx.x < NB) {
        int spins = 0;
        while (__hip_atomic_load(&slots[threadIdx.x * 16], __ATOMIC_RELAXED,
                                 __HIP_MEMORY_SCOPE_AGENT) < target) {
            if (++spins > 50000000) break;                   // bounded: no hang on bug
        }
    }
    __threadfence();                                         // acquire: invalidate stale caches
    __syncthreads();
}

// ---------------- prep kernels ----------------

__global__ void k_embed_x(const float* Es, const float* Ef, const float* Ep, const float* En,
                          const int* value, const int* field, const int* ppos, const int* pneg,
                          float* x) {
    int i = blockIdx.x * 256 + threadIdx.x;
    if (i >= B * L * INE) return;
    int j = i % INE, bl = i / INE;
    float v;
    if (j < 400)      v = Es[(size_t)value[bl] * 400 + j];
    else if (j < 450) v = Ef[(size_t)field[bl] * 50 + (j - 400)];
    else if (j < 455) v = Ep[(size_t)ppos[bl] * 5 + (j - 450)];
    else              v = En[(size_t)pneg[bl] * 5 + (j - 455)];
    x[i] = v;
}

__global__ void k_embed_sent(const float* Es, const int* sent, float* sx) {
    int i = blockIdx.x * 256 + threadIdx.x;
    if (i >= T * B * 400) return;
    int k = i % 400, tb = i / 400;
    int b = tb % B, t = tb / B;
    sx[i] = Es[(size_t)sent[b * T + t] * 400 + k];
}

__global__ void k_transpose(float* dst, const float* src, int K, int G) {
    int i = blockIdx.x * 256 + threadIdx.x;
    if (i >= K * G) return;
    int g = i % G, k = i / G;
    dst[i] = src[(size_t)g * K + k];
}

__global__ void k_pack4(float* dst, const float* src, int U, int Kh) {
    int i = blockIdx.x * 256 + threadIdx.x;
    if (i >= U * Kh * 4) return;
    int g = i & 3, rest = i >> 2;
    int k = rest % Kh, u = rest / Kh;
    dst[i] = src[((size_t)(g * U + u)) * Kh + k];
}

__global__ void k_pack_wcat(float* dst, const float* Wd, const float* Wz, const float* Wo, const float* wl) {
    int i = blockIdx.x * 256 + threadIdx.x;
    if (i >= 500 * OC) return;
    int o = i % OC, d = i / OC;
    float v = 0.f;
    if (o < 500)       v = Wd[(size_t)d * 500 + o];
    else if (o < 560)  v = Wz[(size_t)d * 60 + (o - 500)];
    else if (o < 1060) v = Wo[(size_t)d * 500 + (o - 560)];
    else if (o == 1060) v = wl[d];
    dst[i] = v;
}

__global__ void k_zerod(double* p, int n) {
    int i = blockIdx.x * 256 + threadIdx.x;
    if (i < n) p[i] = 0.0;
}

__global__ void k_zeroi(int* p, int n) {
    int i = blockIdx.x * 256 + threadIdx.x;
    if (i < n) p[i] = 0;
}

// out[t][g][b] = bias[g] + sum_k xs[b,t,k] * Wt[k][g]   (f64 accumulate)
__global__ __launch_bounds__(256) void k_gemm_xw(double* out, const float* xs, int bstride, int tstride,
                                                 const float* Wt, const float* bias, int K, int G) {
    __shared__ float xls[460 * 33];
    int t = blockIdx.x;
    int g = blockIdx.y * 256 + threadIdx.x;
    bool act = g < G;
    for (int i = threadIdx.x; i < 32 * K; i += 256) {
        int b = i / K, k = i - b * K;
        xls[k * 33 + b] = xs[(size_t)b * bstride + (size_t)t * tstride + k];
    }
    __syncthreads();
    double acc[32];
    double bs = act ? (double)bias[g] : 0.0;
#pragma unroll
    for (int b = 0; b < 32; ++b) acc[b] = bs;
    for (int k = 0; k < K; ++k) {
        double w = act ? (double)Wt[(size_t)k * G + g] : 0.0;
        const float* xr = &xls[k * 33];
#pragma unroll
        for (int b = 0; b < 32; ++b) acc[b] += w * (double)xr[b];
    }
    if (act) {
        double* op = out + ((size_t)t * G + g) * 32;
#pragma unroll
        for (int b = 0; b < 32; ++b) op[b] = acc[b];
    }
}

// ---------------- encoder: ONE kernel, 63 blocks, unit-distributed, 100 steps ----------------

__global__ __launch_bounds__(256) void k_enc_steps(const double* xwF, const double* xwB,
                                                   const float* w4enc, double* hG,
                                                   double* eoB, double* hencF, double* cencF,
                                                   int* slots) {
    int tid = threadIdx.x;
    int gt = blockIdx.x * 256 + tid;
    bool act = gt < 16000;
    int dir = 0, u = 0, b = 0;
    if (act) { dir = gt / 8000; int r = gt - dir * 8000; u = r >> 5; b = r & 31; }
    const double* xw = dir ? xwB : xwF;
    const float4* W4 = (const float4*)w4enc + (size_t)(dir * 250 + u) * 250;
    double c = 0.0;
    // hG phase 0 pre-zeroed by prep
    for (int s = 0; s < L; ++s) {
        int ph = s & 1;
        if (act) {
            int tin = dir ? (L - 1 - s) : s;
            double zi = xw[((size_t)tin * 1000 + 0 * HR + u) * 32 + b];
            double zf = xw[((size_t)tin * 1000 + 1 * HR + u) * 32 + b];
            double zg = xw[((size_t)tin * 1000 + 2 * HR + u) * 32 + b];
            double zo = xw[((size_t)tin * 1000 + 3 * HR + u) * 32 + b];
            const double* hp = hG + ph * 16000 + dir * 8000;
#pragma unroll 4
            for (int k = 0; k < 250; ++k) {
                double hv = hp[k * 32 + b];
                float4 w = W4[k];
                zi += (double)w.x * hv; zf += (double)w.y * hv;
                zg += (double)w.z * hv; zo += (double)w.w * hv;
            }
            double cn = dsig(zf) * c + dsig(zi) * tanh(zg);
            double hn = dsig(zo) * tanh(cn);
            c = cn;
            hG[(ph ^ 1) * 16000 + dir * 8000 + u * 32 + b] = hn;
            eoB[((size_t)b * 100 + tin) * 500 + dir * 250 + u] = hn;
            if (s == L - 1) {
                hencF[dir * 8000 + u * 32 + b] = hn;
                cencF[dir * 8000 + u * 32 + b] = cn;
            }
        }
        gbar(slots, s + 1);
    }
}

// replicate torch .view on [2,B,250] -> [B,500] ; write h0 directly into hG_dec phase 0
__global__ void k_scramble(double* hGdec, double* cdec0, const double* hencF, const double* cencF) {
    int gt = blockIdx.x * 256 + threadIdx.x;
    if (gt >= 16000) return;
    int bb = gt / 500, j = gt - bb * 500;
    int d = gt / 8000, rem = gt - d * 8000;
    int bs = rem / 250, us = rem - bs * 250;
    hGdec[j * 32 + bb] = hencF[d * 8000 + us * 32 + bs];
    cdec0[j * 32 + bb] = cencF[d * 8000 + us * 32 + bs];
}

// ---------------- attention precomputes ----------------

__global__ __launch_bounds__(256) void k_e2(const double* eoB, const float* Wo, const float* wl,
                                            double* E2, double* E_wl) {
    __shared__ double eo_s[500];
    int bid = blockIdx.x;              // [0,3200)
    int b = bid / 100, l = bid - b * 100;
    int tid = threadIdx.x;
    for (int j = tid; j < 500; j += 256) eo_s[j] = eoB[((size_t)b * 100 + l) * 500 + j];
    __syncthreads();
#pragma unroll 2
    for (int e = tid; e < 500; e += 256) {
        double acc = 0.0;
        for (int j = 0; j < 500; ++j)
            acc += eo_s[j] * (double)Wo[(size_t)(500 + j) * 500 + e];
        E2[((size_t)b * 100 + l) * 500 + e] = acc;
    }
    if (tid < 64) {
        double p = 0.0;
        for (int j = tid; j < 500; j += 64) p += eo_s[j] * (double)wl[500 + j];
        for (int off = 32; off > 0; off >>= 1) p += __shfl_down(p, off);
        if (tid == 0) E_wl[b * 100 + l] = p;
    }
}

__global__ void k_sxl(const float* sx, const float* wl, double* SXL) {
    int i = blockIdx.x * 256 + threadIdx.x;
    if (i >= 1600) return;
    double acc = 0.0;
    for (int k = 0; k < 400; ++k) acc += (double)sx[(size_t)i * 400 + k] * (double)wl[1000 + k];
    SXL[i] = acc;
}

// ---------------- decoder cells: ONE kernel, 63 blocks, unit-distributed, 50 steps ----------------

__global__ __launch_bounds__(256) void k_dec_steps(const double* cdec0, const double* xwD,
                                                   const float* w4dec, double* hG,
                                                   double* Hd, double* hdecF, double* cdecF,
                                                   int* slots) {
    int tid = threadIdx.x;
    int gt = blockIdx.x * 256 + tid;
    bool act = gt < 16000;
    int u = 0, b = 0;
    if (act) { u = gt >> 5; b = gt & 31; }
    const float4* W4 = (const float4*)w4dec + (size_t)u * 500;
    double c = act ? cdec0[u * 32 + b] : 0.0;
    // hG phase 0 filled by k_scramble
    for (int t = 0; t < T; ++t) {
        int ph = t & 1;
        if (act) {
            double zi = xwD[((size_t)t * 2000 + 0 * HD + u) * 32 + b];
            double zf = xwD[((size_t)t * 2000 + 1 * HD + u) * 32 + b];
            double zg = xwD[((size_t)t * 2000 + 2 * HD + u) * 32 + b];
            double zo = xwD[((size_t)t * 2000 + 3 * HD + u) * 32 + b];
            const double* hp = hG + ph * 16000;
#pragma unroll 4
            for (int k = 0; k < 500; ++k) {
                double hv = hp[k * 32 + b];
                float4 w = W4[k];
                zi += (double)w.x * hv; zf += (double)w.y * hv;
                zg += (double)w.z * hv; zo += (double)w.w * hv;
            }
            double cn = dsig(zf) * c + dsig(zi) * tanh(zg);
            double hn = dsig(zo) * tanh(cn);
            c = cn;
            hG[(ph ^ 1) * 16000 + u * 32 + b] = hn;
            Hd[((size_t)t * 32 + b) * 500 + u] = hn;
            if (t == T - 1) {
                hdecF[u * 32 + b] = hn;
                cdecF[u * 32 + b] = cn;
            }
        }
        gbar(slots, t + 1);
    }
}

// batched h-projections: PROJ[m2][o] = sum_d Hd[m2][d] * Wcat[d][o],  m2 = t*32+b
__global__ __launch_bounds__(256) void k_proj_all(const double* Hd, const float* Wcat, double* PROJ) {
    __shared__ double hrow[500];
    int m2 = blockIdx.x;               // [0,1600)
    int tid = threadIdx.x;
    for (int d = tid; d < 500; d += 256) hrow[d] = Hd[(size_t)m2 * 500 + d];
    __syncthreads();
    for (int o = tid; o < OC; o += 256) {
        double acc = 0.0;
        for (int d = 0; d < 500; ++d) acc += hrow[d] * (double)Wcat[(size_t)d * OC + o];
        PROJ[(size_t)m2 * OC + o] = acc;
    }
}

// batched scores + dual softmax + attn/AD/widx/awl : one block per (t,b)
__global__ __launch_bounds__(256) void k_attn_all(
        const double* PROJ, const double* eoB, const float* x, const double* E_wl, const int* value,
        float* attn_ws, double* AD, double* AWL, int* widx) {
    int bid = blockIdx.x;              // = t*32+b
    int t = bid >> 5, b = bid & 31;
    int tid = threadIdx.x;
    int m = b * T + t;
    __shared__ double hwd_s[500], hz_s[60], sd_s[100], sz_s[100], aL[100];
    __shared__ double red[256];
    __shared__ int ri[256];
    const double* pr = PROJ + (size_t)bid * OC;
    for (int k = tid; k < 500; k += 256) hwd_s[k] = pr[k];
    if (tid < 60) hz_s[tid] = pr[500 + tid];
    __syncthreads();
    int w = tid >> 6, lane = tid & 63;
    for (int l = w; l < 100; l += 4) {
        const double* er = eoB + ((size_t)b * 100 + l) * 500;
        double p = 0.0;
        for (int e = lane; e < 500; e += 64) p += hwd_s[e] * er[e];
        for (int off = 32; off > 0; off >>= 1) p += __shfl_down(p, off);
        if (lane == 0) sd_s[l] = p;
        const float* zr = x + ((size_t)b * 100 + l) * 460 + 400;
        double q = (lane < 60) ? hz_s[lane] * (double)zr[lane] : 0.0;
        for (int off = 32; off > 0; off >>= 1) q += __shfl_down(q, off);
        if (lane == 0) sz_s[l] = q;
    }
    __syncthreads();
    red[tid] = (tid < 100) ? sd_s[tid] : -1e300; __syncthreads();
    for (int o = 128; o > 0; o >>= 1) { if (tid < o) red[tid] = fmax(red[tid], red[tid + o]); __syncthreads(); }
    double md = red[0]; __syncthreads();
    red[tid] = (tid < 100) ? exp(sd_s[tid] - md) : 0.0; __syncthreads();
    for (int o = 128; o > 0; o >>= 1) { if (tid < o) red[tid] += red[tid + o]; __syncthreads(); }
    double Sd = red[0]; __syncthreads();
    red[tid] = (tid < 100) ? sz_s[tid] : -1e300; __syncthreads();
    for (int o = 128; o > 0; o >>= 1) { if (tid < o) red[tid] = fmax(red[tid], red[tid + o]); __syncthreads(); }
    double mz = red[0]; __syncthreads();
    red[tid] = (tid < 100) ? exp(sz_s[tid] - mz) : 0.0; __syncthreads();
    for (int o = 128; o > 0; o >>= 1) { if (tid < o) red[tid] += red[tid + o]; __syncthreads(); }
    double Sz = red[0]; __syncthreads();
    if (tid < 100) aL[tid] = (exp(sd_s[tid] - md) / Sd) * (exp(sz_s[tid] - mz) / Sz);
    __syncthreads();
    red[tid] = (tid < 100) ? aL[tid] : 0.0; __syncthreads();
    for (int o = 128; o > 0; o >>= 1) { if (tid < o) red[tid] += red[tid + o]; __syncthreads(); }
    double Sa = red[0]; __syncthreads();
    if (tid < 100) {
        double av = aL[tid] / (Sa + 1e-3);
        aL[tid] = av;
        attn_ws[(size_t)m * 100 + tid] = (float)av;
        AD[(size_t)m * 100 + tid] = av;
    }
    __syncthreads();
    red[tid] = (tid < 100) ? aL[tid] : -1e300;
    ri[tid]  = (tid < 100) ? tid : 0x7fffffff;
    __syncthreads();
    for (int o = 128; o > 0; o >>= 1) {
        if (tid < o) {
            if (red[tid + o] > red[tid] || (red[tid + o] == red[tid] && ri[tid + o] < ri[tid])) {
                red[tid] = red[tid + o]; ri[tid] = ri[tid + o];
            }
        }
        __syncthreads();
    }
    if (tid == 0) widx[m] = value[b * 100 + ri[0]];
    if (tid < 64) {
        double p = (tid < 100) ? aL[tid] * E_wl[b * 100 + tid] : 0.0;
        if (tid + 64 < 100) p += aL[tid + 64] * E_wl[b * 100 + tid + 64];
        for (int off = 32; off > 0; off >>= 1) p += __shfl_down(p, off);
        if (tid == 0) AWL[m] = p;
    }
}

// outs[m][e] = tanh(hWo1 + a@E2 + b_out); lam[m] = sigmoid(hwl + awl + sxl + b_l)
__global__ __launch_bounds__(256) void k_outs(const double* PROJ, const double* AD, const double* E2,
                                              const double* AWL, const double* SXL,
                                              const float* b_out, const float* b_l,
                                              float* outs32, float* lam_ws) {
    __shared__ double ad_s[100];
    int m = blockIdx.x, tid = threadIdx.x;
    int b = m / T, t = m - b * T;
    if (tid < 100) ad_s[tid] = AD[(size_t)m * 100 + tid];
    __syncthreads();
    const double* pr = PROJ + ((size_t)t * 32 + b) * OC;
#pragma unroll 2
    for (int e = tid; e < 512; e += 256) {
        if (e < 500) {
            double acc = pr[560 + e] + (double)b_out[e];
            const double* e2 = E2 + (size_t)b * 50000 + e;
            for (int l = 0; l < 100; ++l) acc += ad_s[l] * e2[l * 500];
            outs32[(size_t)m * 512 + e] = (float)tanh(acc);
        } else {
            outs32[(size_t)m * 512 + e] = 0.f;
        }
    }
    if (tid == 0)
        lam_ws[m] = (float)dsig(pr[1060] + AWL[m] + SXL[t * 32 + b] + (double)b_l[0]);
}

__global__ void k_hTcT(float* out, const double* hdecF, const double* cdecF) {
    int i = blockIdx.x * 256 + threadIdx.x;
    if (i >= 16000) return;
    int b = i / 500, u = i - b * 500;
    out[OUT_HT + i] = (float)hdecF[u * 32 + b];
    out[OUT_CT + i] = (float)cdecF[u * 32 + b];
}

// ---------------- logits GEMM (f32 vector): d_out = outs @ W_lin^T + b_lin ----------------

__global__ __launch_bounds__(256) void k_gemm_logits_f32(const float* outs32, const float* W_lin,
                                                         const float* b_lin, float* d_out) {
    __shared__ float As[16][68], Bs[16][68];
    int n0 = blockIdx.x * 64, m0 = blockIdx.y * 64;
    int tid = threadIdx.x;
    int ty = tid >> 4, tx = tid & 15;
    int lr = tid >> 2, lc = tid & 3;
    float acc[4][4];
#pragma unroll
    for (int i = 0; i < 4; ++i)
#pragma unroll
        for (int j = 0; j < 4; ++j) acc[i][j] = 0.f;

    for (int k0 = 0; k0 < 512; k0 += 16) {
        int k4 = k0 + lc * 4;
        float4 av = *(const float4*)(outs32 + (size_t)(m0 + lr) * 512 + k4);
        int n = n0 + lr;
        float4 bv;
        if (n < VS && k4 < 500) bv = *(const float4*)(W_lin + (size_t)n * 500 + k4);
        else bv = make_float4(0.f, 0.f, 0.f, 0.f);
        __syncthreads();
        As[lc * 4 + 0][lr] = av.x; As[lc * 4 + 1][lr] = av.y;
        As[lc * 4 + 2][lr] = av.z; As[lc * 4 + 3][lr] = av.w;
        Bs[lc * 4 + 0][lr] = bv.x; Bs[lc * 4 + 1][lr] = bv.y;
        Bs[lc * 4 + 2][lr] = bv.z; Bs[lc * 4 + 3][lr] = bv.w;
        __syncthreads();
#pragma unroll
        for (int kk = 0; kk < 16; ++kk) {
            float4 a4 = *(const float4*)&As[kk][ty * 4];
            float4 b4 = *(const float4*)&Bs[kk][tx * 4];
            float ar[4] = {a4.x, a4.y, a4.z, a4.w};
            float br[4] = {b4.x, b4.y, b4.z, b4.w};
#pragma unroll
            for (int i = 0; i < 4; ++i)
#pragma unroll
                for (int j = 0; j < 4; ++j) acc[i][j] += ar[i] * br[j];
        }
    }
#pragma unroll
    for (int j = 0; j < 4; ++j) {
        int n = n0 + tx * 4 + j;
        if (n < VS) {
            float bl = b_lin[n];
#pragma unroll
            for (int i = 0; i < 4; ++i) {
                int mm = m0 + ty * 4 + i;
                d_out[(size_t)mm * VS + n] = acc[i][j] + bl;
            }
        }
    }
}

// ---------------- softmax passes ----------------

__global__ void k_red1(const float* d_out, float* LS1) {
    int m = blockIdx.x, tid = threadIdx.x;
    const float* row = d_out + (size_t)m * VS;
    __shared__ float red[256];
    float lm = -3e38f;
    for (int v = tid; v < VS; v += 256) lm = fmaxf(lm, row[v]);
    red[tid] = lm; __syncthreads();
    for (int o = 128; o > 0; o >>= 1) { if (tid < o) red[tid] = fmaxf(red[tid], red[tid + o]); __syncthreads(); }
    float m1 = red[0]; __syncthreads();
    float ls = 0.f;
    for (int v = tid; v < VS; v += 256) ls += expf(row[v] - m1);
    red[tid] = ls; __syncthreads();
    for (int o = 128; o > 0; o >>= 1) { if (tid < o) red[tid] += red[tid + o]; __syncthreads(); }
    if (tid == 0) LS1[m] = m1 + logf(red[0]);
}

__global__ __launch_bounds__(256) void k_plexmix(float* d_out, const float* attn_ws, const float* align_prob,
                                                 const float* lam_ws, const float* LS1) {
    int b = blockIdx.y, v0 = blockIdx.x * 64, tid = threadIdx.x;
    __shared__ float attn_s[50 * 100];
    __shared__ float al[100 * 64];
    for (int i = tid; i < 5000; i += 256) attn_s[i] = attn_ws[(size_t)b * 5000 + i];
    for (int i = tid; i < 6400; i += 256) {
        int l = i >> 6, j = i & 63;
        int v = v0 + j;
        al[i] = (v < VS) ? align_prob[((size_t)b * 100 + l) * VS + v] : 0.f;
    }
    __syncthreads();
    for (int idx = tid; idx < 50 * 64; idx += 256) {
        int t = idx >> 6, j = idx & 63;
        int v = v0 + j;
        if (v < VS) {
            float acc = 0.f;
            for (int l = 0; l < 100; ++l) acc += attn_s[t * 100 + l] * al[l * 64 + j];
            int m = b * T + t;
            size_t p = (size_t)m * VS + v;
            float lamv = lam_ws[m];
            d_out[p] = lamv * acc + (1.f - lamv) * (d_out[p] - LS1[m]);
        }
    }
}

__global__ void k_final2(float* d_out, const float* E_target) {
    int m = blockIdx.x, tid = threadIdx.x;
    float* row = d_out + (size_t)m * VS;
    __shared__ float sm[256], ss[256], sbv[256];
    __shared__ int sbi[256];
    float rm = -3e38f, rs = 0.f, bv = -3e38f; int bi = 0;
    for (int v = tid; v < VS; v += 256) {
        float xv = row[v];
        if (xv > bv) { bv = xv; bi = v; }
        if (xv > rm) { rs = rs * expf(rm - xv) + 1.f; rm = xv; }
        else rs += expf(xv - rm);
    }
    sm[tid] = rm; ss[tid] = rs; sbv[tid] = bv; sbi[tid] = bi;
    __syncthreads();
    for (int o = 128; o > 0; o >>= 1) {
        if (tid < o) {
            float m1 = sm[tid], m2 = sm[tid + o];
            float M = fmaxf(m1, m2);
            ss[tid] = ss[tid] * expf(m1 - M) + ss[tid + o] * expf(m2 - M);
            sm[tid] = M;
            if (sbv[tid + o] > sbv[tid] || (sbv[tid + o] == sbv[tid] && sbi[tid + o] < sbi[tid])) {
                sbv[tid] = sbv[tid + o]; sbi[tid] = sbi[tid + o];
            }
        }
        __syncthreads();
    }
    float ls2 = sm[0] + logf(ss[0]);
    int amax = sbi[0];
    for (int v = tid; v < VS; v += 256) row[v] -= ls2;
    for (int j = tid; j < 300; j += 256)
        d_out[OUT_DP + (size_t)m * 300 + j] = E_target[(size_t)amax * 300 + j];
}

__global__ void k_attnpred2(const int* widx, const float* E_target, float* d_out) {
    int i = blockIdx.x * 256 + threadIdx.x;
    if (i >= 1600 * 300) return;
    int m = i / 300, j = i - m * 300;
    d_out[OUT_AP + i] = E_target[(size_t)widx[m] * 300 + j];
}

// ---------------- launch ----------------

extern "C" void kernel_launch(void* const* d_in, const int* in_sizes, int n_in,
                              void* d_out_v, int out_size, void* d_ws, size_t ws_size,
                              hipStream_t stream) {
    const float* align_prob = (const float*)d_in[1];
    const float* E_sent     = (const float*)d_in[2];
    const float* E_field    = (const float*)d_in[3];
    const float* E_ppos     = (const float*)d_in[4];
    const float* E_pneg     = (const float*)d_in[5];
    const float* E_target   = (const float*)d_in[6];
    const float* enc_Wih_f  = (const float*)d_in[7];
    const float* enc_Whh_f  = (const float*)d_in[8];
    const float* enc_b_f    = (const float*)d_in[9];
    const float* enc_Wih_b  = (const float*)d_in[10];
    const float* enc_Whh_b  = (const float*)d_in[11];
    const float* enc_b_b    = (const float*)d_in[12];
    const float* dec_Wih    = (const float*)d_in[13];
    const float* dec_Whh    = (const float*)d_in[14];
    const float* dec_b      = (const float*)d_in[15];
    const float* W_d        = (const float*)d_in[16];
    const float* W_z        = (const float*)d_in[17];
    const float* W_out      = (const float*)d_in[18];
    const float* b_out      = (const float*)d_in[19];
    const float* w_l        = (const float*)d_in[20];
    const float* b_l        = (const float*)d_in[21];
    const float* W_lin      = (const float*)d_in[22];
    const float* b_lin      = (const float*)d_in[23];
    const int* sent  = (const int*)d_in[24];
    const int* value = (const int*)d_in[25];
    const int* field = (const int*)d_in[26];
    const int* ppos  = (const int*)d_in[27];
    const int* pneg  = (const int*)d_in[28];

    char* ws = (char*)d_ws;
    float*  x      = (float*)(ws + O_X);
    float*  sx     = (float*)(ws + O_SX);
    float*  WihfT  = (float*)(ws + O_WIHFT);
    float*  WihbT  = (float*)(ws + O_WIHBT);
    float*  WdecT  = (float*)(ws + O_WDECT);
    float*  w4enc  = (float*)(ws + O_W4ENC);
    float*  w4dec  = (float*)(ws + O_W4DEC);
    float*  Wcat   = (float*)(ws + O_WCAT);
    double* xwF    = (double*)(ws + O_XWF);
    double* xwB    = (double*)(ws + O_XWB);
    double* xwD    = (double*)(ws + O_XWD);
    double* eoB    = (double*)(ws + O_EOB);
    double* E2     = (double*)(ws + O_E2);
    double* PROJ   = (double*)(ws + O_PROJ);
    double* Hd     = (double*)(ws + O_HD);
    double* hGenc  = (double*)(ws + O_HGENC);
    double* hGdec  = (double*)(ws + O_HGDEC);
    double* hencF  = (double*)(ws + O_HENCF);
    double* cencF  = (double*)(ws + O_CENCF);
    double* cdec0  = (double*)(ws + O_CDEC0);
    double* hdecF  = (double*)(ws + O_HDECF);
    double* cdecF  = (double*)(ws + O_CDECF);
    double* AD     = (double*)(ws + O_AD);
    float*  attn_ws= (float*)(ws + O_ATTN);
    double* E_wl   = (double*)(ws + O_EWL);
    double* SXL    = (double*)(ws + O_SXL);
    double* AWL    = (double*)(ws + O_AWL);
    float*  lam_ws = (float*)(ws + O_LAM);
    float*  LS1    = (float*)(ws + O_LS1);
    int*    widx   = (int*)(ws + O_WIDX);
    int*    barE   = (int*)(ws + O_BAR);
    int*    barD   = (int*)(ws + O_BAR) + 64 * 16;
    float*  outs32 = (float*)(ws + O_OUTS);
    float* out = (float*)d_out_v;

    // ---- prep (parallel) ----
    k_embed_x<<<(B * L * INE + 255) / 256, 256, 0, stream>>>(E_sent, E_field, E_ppos, E_pneg,
                                                             value, field, ppos, pneg, x);
    k_embed_sent<<<(T * B * 400 + 255) / 256, 256, 0, stream>>>(E_sent, sent, sx);
    k_transpose<<<(460 * 1000 + 255) / 256, 256, 0, stream>>>(WihfT, enc_Wih_f, 460, 1000);
    k_transpose<<<(460 * 1000 + 255) / 256, 256, 0, stream>>>(WihbT, enc_Wih_b, 460, 1000);
    k_transpose<<<(400 * 2000 + 255) / 256, 256, 0, stream>>>(WdecT, dec_Wih, 400, 2000);
    k_pack4<<<(250 * 250 * 4 + 255) / 256, 256, 0, stream>>>(w4enc, enc_Whh_f, 250, 250);
    k_pack4<<<(250 * 250 * 4 + 255) / 256, 256, 0, stream>>>(w4enc + 250000, enc_Whh_b, 250, 250);
    k_pack4<<<(500 * 500 * 4 + 255) / 256, 256, 0, stream>>>(w4dec, dec_Whh, 500, 500);
    k_pack_wcat<<<(500 * OC + 255) / 256, 256, 0, stream>>>(Wcat, W_d, W_z, W_out, w_l);
    k_zerod<<<(16000 + 255) / 256, 256, 0, stream>>>(hGenc, 16000);   // enc h phase 0
    k_zeroi<<<8, 256, 0, stream>>>(barE, 2048);                        // both barrier slot arrays
    k_sxl<<<(1600 + 255) / 256, 256, 0, stream>>>(sx, w_l, SXL);
    {
        dim3 g1(100, 4); k_gemm_xw<<<g1, 256, 0, stream>>>(xwF, x, L * INE, INE, WihfT, enc_b_f, 460, 1000);
        dim3 g2(100, 4); k_gemm_xw<<<g2, 256, 0, stream>>>(xwB, x, L * INE, INE, WihbT, enc_b_b, 460, 1000);
        dim3 g3(50, 8);  k_gemm_xw<<<g3, 256, 0, stream>>>(xwD, sx, 400, B * 400, WdecT, dec_b, 400, 2000);
    }

    // ---- encoder: ONE kernel, unit-distributed, slot barrier ----
    k_enc_steps<<<NB, 256, 0, stream>>>(xwF, xwB, w4enc, hGenc, eoB, hencF, cencF, barE);
    k_scramble<<<63, 256, 0, stream>>>(hGdec, cdec0, hencF, cencF);
    k_e2<<<3200, 256, 0, stream>>>(eoB, W_out, w_l, E2, E_wl);

    // ---- decoder cells: ONE kernel ----
    k_dec_steps<<<NB, 256, 0, stream>>>(cdec0, xwD, w4dec, hGdec, Hd, hdecF, cdecF, barD);
    k_hTcT<<<63, 256, 0, stream>>>(out, hdecF, cdecF);

    // ---- attention: fully batched over all (t,b) ----
    k_proj_all<<<1600, 256, 0, stream>>>(Hd, Wcat, PROJ);
    k_attn_all<<<1600, 256, 0, stream>>>(PROJ, eoB, x, E_wl, value, attn_ws, AD, AWL, widx);
    k_outs<<<1600, 256, 0, stream>>>(PROJ, AD, E2, AWL, SXL, b_out, b_l, outs32, lam_ws);

    // ---- output head ----
    {
        dim3 gg(313, 25);
        k_gemm_logits_f32<<<gg, 256, 0, stream>>>(outs32, W_lin, b_lin, out);
    }
    k_red1<<<1600, 256, 0, stream>>>(out, LS1);
    {
        dim3 gp(313, 32);
        k_plexmix<<<gp, 256, 0, stream>>>(out, attn_ws, align_prob, lam_ws, LS1);
    }
    k_final2<<<1600, 256, 0, stream>>>(out, E_target);
    k_attnpred2<<<(1600 * 300 + 255) / 256, 256, 0, stream>>>(widx, E_target, out);
}

// Round 8
// 7547.200 us; speedup vs baseline: 1.1681x; 1.1681x over previous
//
#include <hip/hip_runtime.h>

#define DI __device__ __forceinline__

constexpr int B = 32, L = 100, T = 50;
constexpr int VS = 20000;
constexpr int HR = 250, HD = 500;
constexpr int INE = 460;
constexpr int OC = 1072;   // padded Wcat columns: 500 hwd | 60 hz | 500 hWo1 | 1 hwl | pad
constexpr int NBE = 64;    // encoder blocks (32 per direction)
constexpr int NBD = 63;    // decoder blocks

// ---- workspace byte offsets ----
constexpr size_t O_X      = 0;                      // x [B][L][460] f32
constexpr size_t O_SX     = 5888000;                // sent_x [T][B][400] f32
constexpr size_t O_WIHFT  = 8448000;                // enc_Wih_f^T [460][1000] f32
constexpr size_t O_WIHBT  = 10288000;
constexpr size_t O_WDECT  = 12128000;               // dec_Wih^T [400][2000] f32
constexpr size_t O_W4ENC  = 15328000;               // [2dir][250u][250k][4g] f32
constexpr size_t O_W4DEC  = 17328000;               // [500u][500k][4g] f32
constexpr size_t O_WCAT   = 21328000;               // [500][1072] f32
constexpr size_t O_XWF    = 23472000;               // [100][1000][32] f64
constexpr size_t O_XWB    = 49072000;
constexpr size_t O_XWD    = 74672000;               // [50][2000][32] f64
constexpr size_t O_EOB    = 100272000;              // enc_out [32][100][500] f64
constexpr size_t O_E2     = 113072000;              // [32][100][500] f64
constexpr size_t O_PROJ   = 125872000;              // [50][32][1072] f64
constexpr size_t O_HD     = 139593600;              // [1600][500] f64 (row t*32+b)
constexpr size_t O_HGENC  = 145993600;              // [2ph][16000] f64
constexpr size_t O_HGDEC  = 146249600;              // [2ph][16000] f64
constexpr size_t O_HENCF  = 146505600;              // [2dir][250][32] f64 final
constexpr size_t O_CENCF  = 146633600;
constexpr size_t O_CDEC0  = 146761600;              // [500][32] f64 scrambled c init
constexpr size_t O_HDECF  = 146889600;              // [500][32] f64 final
constexpr size_t O_CDECF  = 147017600;
constexpr size_t O_AD     = 147145600;              // a f64 [1600][100]
constexpr size_t O_ATTN   = 148425600;              // [32][50][100] f32
constexpr size_t O_EWL    = 149065600;              // [32][100] f64
constexpr size_t O_SXL    = 149091200;              // [1600] f64 (t*32+b)
constexpr size_t O_AWL    = 149104000;              // [1600] f64 (b*50+t)
constexpr size_t O_LAM    = 149116800;              // [1600] f32
constexpr size_t O_LS1    = 149123200;              // [1600] f32
constexpr size_t O_WIDX   = 149129600;              // [1600] int
constexpr size_t O_BAR    = 149136000;              // 2 x 64 slots x 16 ints (64B padded)
constexpr size_t O_OUTS   = 149144192;              // outs f32 [1600][512]
// end ~152.4 MB (<=158.4MB proven)

// output element offsets (f32)
constexpr size_t OUT_HT  = 32000000;
constexpr size_t OUT_CT  = 32016000;
constexpr size_t OUT_AP  = 32032000;
constexpr size_t OUT_DP  = 32512000;

DI double dsig(double x) { return 1.0 / (1.0 + exp(-x)); }

// coherent (cache-bypassing, agent-scope) load/store — the ONLY cross-block data path
DI double cld(const double* p) {
    return __hip_atomic_load(p, __ATOMIC_RELAXED, __HIP_MEMORY_SCOPE_AGENT);
}
DI void cst(double* p, double v) {
    __hip_atomic_store(p, v, __ATOMIC_RELAXED, __HIP_MEMORY_SCOPE_AGENT);
}

// fence-free barrier: __syncthreads drains every wave's vmcnt (coherent stores then globally
// visible), signal own slot with a coherent store, wave0 lanes poll all slots coherently.
DI void gbar(int* slots, int target, int nb) {
    __syncthreads();                       // drains vmcnt/lgkmcnt for ALL waves (release)
    if (threadIdx.x == 0)
        __hip_atomic_store(&slots[blockIdx.x * 16], target,
                           __ATOMIC_RELAXED, __HIP_MEMORY_SCOPE_AGENT);
    if ((int)threadIdx.x < nb) {
        int spins = 0;
        while (__hip_atomic_load(&slots[threadIdx.x * 16], __ATOMIC_RELAXED,
                                 __HIP_MEMORY_SCOPE_AGENT) < target) {
            if (++spins > 100000000) break;   // bounded: no hang on bug
        }
    }
    asm volatile("" ::: "memory");         // compiler barrier only — no HW invalidate
    __syncthreads();
}

// ---------------- prep kernels ----------------

__global__ void k_embed_x(const float* Es, const float* Ef, const float* Ep, const float* En,
                          const int* value, const int* field, const int* ppos, const int* pneg,
                          float* x) {
    int i = blockIdx.x * 256 + threadIdx.x;
    if (i >= B * L * INE) return;
    int j = i % INE, bl = i / INE;
    float v;
    if (j < 400)      v = Es[(size_t)value[bl] * 400 + j];
    else if (j < 450) v = Ef[(size_t)field[bl] * 50 + (j - 400)];
    else if (j < 455) v = Ep[(size_t)ppos[bl] * 5 + (j - 450)];
    else              v = En[(size_t)pneg[bl] * 5 + (j - 455)];
    x[i] = v;
}

__global__ void k_embed_sent(const float* Es, const int* sent, float* sx) {
    int i = blockIdx.x * 256 + threadIdx.x;
    if (i >= T * B * 400) return;
    int k = i % 400, tb = i / 400;
    int b = tb % B, t = tb / B;
    sx[i] = Es[(size_t)sent[b * T + t] * 400 + k];
}

__global__ void k_transpose(float* dst, const float* src, int K, int G) {
    int i = blockIdx.x * 256 + threadIdx.x;
    if (i >= K * G) return;
    int g = i % G, k = i / G;
    dst[i] = src[(size_t)g * K + k];
}

__global__ void k_pack4(float* dst, const float* src, int U, int Kh) {
    int i = blockIdx.x * 256 + threadIdx.x;
    if (i >= U * Kh * 4) return;
    int g = i & 3, rest = i >> 2;
    int k = rest % Kh, u = rest / Kh;
    dst[i] = src[((size_t)(g * U + u)) * Kh + k];
}

__global__ void k_pack_wcat(float* dst, const float* Wd, const float* Wz, const float* Wo, const float* wl) {
    int i = blockIdx.x * 256 + threadIdx.x;
    if (i >= 500 * OC) return;
    int o = i % OC, d = i / OC;
    float v = 0.f;
    if (o < 500)       v = Wd[(size_t)d * 500 + o];
    else if (o < 560)  v = Wz[(size_t)d * 60 + (o - 500)];
    else if (o < 1060) v = Wo[(size_t)d * 500 + (o - 560)];
    else if (o == 1060) v = wl[d];
    dst[i] = v;
}

__global__ void k_zerod(double* p, int n) {
    int i = blockIdx.x * 256 + threadIdx.x;
    if (i < n) p[i] = 0.0;
}

__global__ void k_zeroi(int* p, int n) {
    int i = blockIdx.x * 256 + threadIdx.x;
    if (i < n) p[i] = 0;
}

// out[t][g][b] = bias[g] + sum_k xs[b,t,k] * Wt[k][g]   (f64 accumulate)
__global__ __launch_bounds__(256) void k_gemm_xw(double* out, const float* xs, int bstride, int tstride,
                                                 const float* Wt, const float* bias, int K, int G) {
    __shared__ float xls[460 * 33];
    int t = blockIdx.x;
    int g = blockIdx.y * 256 + threadIdx.x;
    bool act = g < G;
    for (int i = threadIdx.x; i < 32 * K; i += 256) {
        int b = i / K, k = i - b * K;
        xls[k * 33 + b] = xs[(size_t)b * bstride + (size_t)t * tstride + k];
    }
    __syncthreads();
    double acc[32];
    double bs = act ? (double)bias[g] : 0.0;
#pragma unroll
    for (int b = 0; b < 32; ++b) acc[b] = bs;
    for (int k = 0; k < K; ++k) {
        double w = act ? (double)Wt[(size_t)k * G + g] : 0.0;
        const float* xr = &xls[k * 33];
#pragma unroll
        for (int b = 0; b < 32; ++b) acc[b] += w * (double)xr[b];
    }
    if (act) {
        double* op = out + ((size_t)t * G + g) * 32;
#pragma unroll
        for (int b = 0; b < 32; ++b) op[b] = acc[b];
    }
}

// ---------------- encoder: 64 blocks (32/dir), LDS-staged h, fence-free barrier ----------------

__global__ __launch_bounds__(256) void k_enc_steps(const double* xwF, const double* xwB,
                                                   const float* w4enc, double* hG,
                                                   double* eoB, double* hencF, double* cencF,
                                                   int* slots) {
    __shared__ double hL[8000];               // 64 KB: this direction's h vector
    int tid = threadIdx.x;
    int bid = blockIdx.x;
    int dir = bid >> 5;                       // blocks 0-31: dir0, 32-63: dir1
    int g = (bid & 31) * 256 + tid;           // [0,8192)
    bool act = g < 8000;
    int u = act ? (g >> 5) : 0;
    int b = act ? (g & 31) : 0;
    const double* xw = dir ? xwB : xwF;
    const float4* W4 = (const float4*)w4enc + (size_t)(dir * 250 + u) * 250;
    double c = 0.0;
    // hG phase 0 pre-zeroed by prep (normal stores, flushed at that kernel's end)
    for (int s = 0; s < L; ++s) {
        int ph = s & 1;
        const double* hsrc = hG + ph * 16000 + dir * 8000;
        for (int i = tid; i < 8000; i += 256) hL[i] = cld(&hsrc[i]);   // coherent stage
        __syncthreads();
        if (act) {
            int tin = dir ? (L - 1 - s) : s;
            double zi = xw[((size_t)tin * 1000 + 0 * HR + u) * 32 + b];
            double zf = xw[((size_t)tin * 1000 + 1 * HR + u) * 32 + b];
            double zg = xw[((size_t)tin * 1000 + 2 * HR + u) * 32 + b];
            double zo = xw[((size_t)tin * 1000 + 3 * HR + u) * 32 + b];
#pragma unroll 4
            for (int k = 0; k < 250; ++k) {
                double hv = hL[k * 32 + b];
                float4 w = W4[k];                 // cached — never invalidated
                zi += (double)w.x * hv; zf += (double)w.y * hv;
                zg += (double)w.z * hv; zo += (double)w.w * hv;
            }
            double cn = dsig(zf) * c + dsig(zi) * tanh(zg);
            double hn = dsig(zo) * tanh(cn);
            c = cn;
            cst(&hG[(ph ^ 1) * 16000 + dir * 8000 + u * 32 + b], hn);  // coherent publish
            eoB[((size_t)b * 100 + tin) * 500 + dir * 250 + u] = hn;   // normal (post-kernel reader)
            if (s == L - 1) {
                hencF[dir * 8000 + u * 32 + b] = hn;
                cencF[dir * 8000 + u * 32 + b] = cn;
            }
        }
        gbar(slots, s + 1, NBE);
    }
}

// replicate torch .view on [2,B,250] -> [B,500] ; write h0 directly into hG_dec phase 0
__global__ void k_scramble(double* hGdec, double* cdec0, const double* hencF, const double* cencF) {
    int gt = blockIdx.x * 256 + threadIdx.x;
    if (gt >= 16000) return;
    int bb = gt / 500, j = gt - bb * 500;
    int d = gt / 8000, rem = gt - d * 8000;
    int bs = rem / 250, us = rem - bs * 250;
    hGdec[j * 32 + bb] = hencF[d * 8000 + us * 32 + bs];
    cdec0[j * 32 + bb] = cencF[d * 8000 + us * 32 + bs];
}

// ---------------- attention precomputes ----------------

__global__ __launch_bounds__(256) void k_e2(const double* eoB, const float* Wo, const float* wl,
                                            double* E2, double* E_wl) {
    __shared__ double eo_s[500];
    int bid = blockIdx.x;              // [0,3200)
    int b = bid / 100, l = bid - b * 100;
    int tid = threadIdx.x;
    for (int j = tid; j < 500; j += 256) eo_s[j] = eoB[((size_t)b * 100 + l) * 500 + j];
    __syncthreads();
#pragma unroll 2
    for (int e = tid; e < 500; e += 256) {
        double acc = 0.0;
        for (int j = 0; j < 500; ++j)
            acc += eo_s[j] * (double)Wo[(size_t)(500 + j) * 500 + e];
        E2[((size_t)b * 100 + l) * 500 + e] = acc;
    }
    if (tid < 64) {
        double p = 0.0;
        for (int j = tid; j < 500; j += 64) p += eo_s[j] * (double)wl[500 + j];
        for (int off = 32; off > 0; off >>= 1) p += __shfl_down(p, off);
        if (tid == 0) E_wl[b * 100 + l] = p;
    }
}

__global__ void k_sxl(const float* sx, const float* wl, double* SXL) {
    int i = blockIdx.x * 256 + threadIdx.x;
    if (i >= 1600) return;
    double acc = 0.0;
    for (int k = 0; k < 400; ++k) acc += (double)sx[(size_t)i * 400 + k] * (double)wl[1000 + k];
    SXL[i] = acc;
}

// ---------------- decoder cells: 63 blocks, chunked LDS-staged h, fence-free barrier ----------------

__global__ __launch_bounds__(256) void k_dec_steps(const double* cdec0, const double* xwD,
                                                   const float* w4dec, double* hG,
                                                   double* Hd, double* hdecF, double* cdecF,
                                                   int* slots) {
    __shared__ double hL[8000];               // 64 KB: one k-half of h
    int tid = threadIdx.x;
    int gt = blockIdx.x * 256 + tid;
    bool act = gt < 16000;
    int u = act ? (gt >> 5) : 0;
    int b = act ? (gt & 31) : 0;
    const float4* W4 = (const float4*)w4dec + (size_t)u * 500;
    double c = act ? cdec0[u * 32 + b] : 0.0;
    // hG phase 0 filled by k_scramble (normal stores, flushed at kernel end)
    for (int t = 0; t < T; ++t) {
        int ph = t & 1;
        const double* hsrc = hG + ph * 16000;
        double zi = 0.0, zf = 0.0, zg = 0.0, zo = 0.0;
        if (act) {
            zi = xwD[((size_t)t * 2000 + 0 * HD + u) * 32 + b];
            zf = xwD[((size_t)t * 2000 + 1 * HD + u) * 32 + b];
            zg = xwD[((size_t)t * 2000 + 2 * HD + u) * 32 + b];
            zo = xwD[((size_t)t * 2000 + 3 * HD + u) * 32 + b];
        }
        // chunk 0: k in [0,250)
        for (int i = tid; i < 8000; i += 256) hL[i] = cld(&hsrc[i]);
        __syncthreads();
        if (act) {
#pragma unroll 4
            for (int k = 0; k < 250; ++k) {
                double hv = hL[k * 32 + b];
                float4 w = W4[k];
                zi += (double)w.x * hv; zf += (double)w.y * hv;
                zg += (double)w.z * hv; zo += (double)w.w * hv;
            }
        }
        __syncthreads();
        // chunk 1: k in [250,500)
        for (int i = tid; i < 8000; i += 256) hL[i] = cld(&hsrc[8000 + i]);
        __syncthreads();
        if (act) {
#pragma unroll 4
            for (int k = 0; k < 250; ++k) {
                double hv = hL[k * 32 + b];
                float4 w = W4[250 + k];
                zi += (double)w.x * hv; zf += (double)w.y * hv;
                zg += (double)w.z * hv; zo += (double)w.w * hv;
            }
            double cn = dsig(zf) * c + dsig(zi) * tanh(zg);
            double hn = dsig(zo) * tanh(cn);
            c = cn;
            cst(&hG[(ph ^ 1) * 16000 + u * 32 + b], hn);               // coherent publish
            Hd[((size_t)t * 32 + b) * 500 + u] = hn;                   // normal (post-kernel)
            if (t == T - 1) {
                hdecF[u * 32 + b] = hn;
                cdecF[u * 32 + b] = cn;
            }
        }
        gbar(slots, t + 1, NBD);
    }
}

// batched h-projections: PROJ[m2][o] = sum_d Hd[m2][d] * Wcat[d][o],  m2 = t*32+b
__global__ __launch_bounds__(256) void k_proj_all(const double* Hd, const float* Wcat, double* PROJ) {
    __shared__ double hrow[500];
    int m2 = blockIdx.x;               // [0,1600)
    int tid = threadIdx.x;
    for (int d = tid; d < 500; d += 256) hrow[d] = Hd[(size_t)m2 * 500 + d];
    __syncthreads();
    for (int o = tid; o < OC; o += 256) {
        double acc = 0.0;
        for (int d = 0; d < 500; ++d) acc += hrow[d] * (double)Wcat[(size_t)d * OC + o];
        PROJ[(size_t)m2 * OC + o] = acc;
    }
}

// batched scores + dual softmax + attn/AD/widx/awl : one block per (t,b)
__global__ __launch_bounds__(256) void k_attn_all(
        const double* PROJ, const double* eoB, const float* x, const double* E_wl, const int* value,
        float* attn_ws, double* AD, double* AWL, int* widx) {
    int bid = blockIdx.x;              // = t*32+b
    int t = bid >> 5, b = bid & 31;
    int tid = threadIdx.x;
    int m = b * T + t;
    __shared__ double hwd_s[500], hz_s[60], sd_s[100], sz_s[100], aL[100];
    __shared__ double red[256];
    __shared__ int ri[256];
    const double* pr = PROJ + (size_t)bid * OC;
    for (int k = tid; k < 500; k += 256) hwd_s[k] = pr[k];
    if (tid < 60) hz_s[tid] = pr[500 + tid];
    __syncthreads();
    int w = tid >> 6, lane = tid & 63;
    for (int l = w; l < 100; l += 4) {
        const double* er = eoB + ((size_t)b * 100 + l) * 500;
        double p = 0.0;
        for (int e = lane; e < 500; e += 64) p += hwd_s[e] * er[e];
        for (int off = 32; off > 0; off >>= 1) p += __shfl_down(p, off);
        if (lane == 0) sd_s[l] = p;
        const float* zr = x + ((size_t)b * 100 + l) * 460 + 400;
        double q = (lane < 60) ? hz_s[lane] * (double)zr[lane] : 0.0;
        for (int off = 32; off > 0; off >>= 1) q += __shfl_down(q, off);
        if (lane == 0) sz_s[l] = q;
    }
    __syncthreads();
    red[tid] = (tid < 100) ? sd_s[tid] : -1e300; __syncthreads();
    for (int o = 128; o > 0; o >>= 1) { if (tid < o) red[tid] = fmax(red[tid], red[tid + o]); __syncthreads(); }
    double md = red[0]; __syncthreads();
    red[tid] = (tid < 100) ? exp(sd_s[tid] - md) : 0.0; __syncthreads();
    for (int o = 128; o > 0; o >>= 1) { if (tid < o) red[tid] += red[tid + o]; __syncthreads(); }
    double Sd = red[0]; __syncthreads();
    red[tid] = (tid < 100) ? sz_s[tid] : -1e300; __syncthreads();
    for (int o = 128; o > 0; o >>= 1) { if (tid < o) red[tid] = fmax(red[tid], red[tid + o]); __syncthreads(); }
    double mz = red[0]; __syncthreads();
    red[tid] = (tid < 100) ? exp(sz_s[tid] - mz) : 0.0; __syncthreads();
    for (int o = 128; o > 0; o >>= 1) { if (tid < o) red[tid] += red[tid + o]; __syncthreads(); }
    double Sz = red[0]; __syncthreads();
    if (tid < 100) aL[tid] = (exp(sd_s[tid] - md) / Sd) * (exp(sz_s[tid] - mz) / Sz);
    __syncthreads();
    red[tid] = (tid < 100) ? aL[tid] : 0.0; __syncthreads();
    for (int o = 128; o > 0; o >>= 1) { if (tid < o) red[tid] += red[tid + o]; __syncthreads(); }
    double Sa = red[0]; __syncthreads();
    if (tid < 100) {
        double av = aL[tid] / (Sa + 1e-3);
        aL[tid] = av;
        attn_ws[(size_t)m * 100 + tid] = (float)av;
        AD[(size_t)m * 100 + tid] = av;
    }
    __syncthreads();
    red[tid] = (tid < 100) ? aL[tid] : -1e300;
    ri[tid]  = (tid < 100) ? tid : 0x7fffffff;
    __syncthreads();
    for (int o = 128; o > 0; o >>= 1) {
        if (tid < o) {
            if (red[tid + o] > red[tid] || (red[tid + o] == red[tid] && ri[tid + o] < ri[tid])) {
                red[tid] = red[tid + o]; ri[tid] = ri[tid + o];
            }
        }
        __syncthreads();
    }
    if (tid == 0) widx[m] = value[b * 100 + ri[0]];
    if (tid < 64) {
        double p = (tid < 100) ? aL[tid] * E_wl[b * 100 + tid] : 0.0;
        if (tid + 64 < 100) p += aL[tid + 64] * E_wl[b * 100 + tid + 64];
        for (int off = 32; off > 0; off >>= 1) p += __shfl_down(p, off);
        if (tid == 0) AWL[m] = p;
    }
}

// outs[m][e] = tanh(hWo1 + a@E2 + b_out); lam[m] = sigmoid(hwl + awl + sxl + b_l)
__global__ __launch_bounds__(256) void k_outs(const double* PROJ, const double* AD, const double* E2,
                                              const double* AWL, const double* SXL,
                                              const float* b_out, const float* b_l,
                                              float* outs32, float* lam_ws) {
    __shared__ double ad_s[100];
    int m = blockIdx.x, tid = threadIdx.x;
    int b = m / T, t = m - b * T;
    if (tid < 100) ad_s[tid] = AD[(size_t)m * 100 + tid];
    __syncthreads();
    const double* pr = PROJ + ((size_t)t * 32 + b) * OC;
#pragma unroll 2
    for (int e = tid; e < 512; e += 256) {
        if (e < 500) {
            double acc = pr[560 + e] + (double)b_out[e];
            const double* e2 = E2 + (size_t)b * 50000 + e;
            for (int l = 0; l < 100; ++l) acc += ad_s[l] * e2[l * 500];
            outs32[(size_t)m * 512 + e] = (float)tanh(acc);
        } else {
            outs32[(size_t)m * 512 + e] = 0.f;
        }
    }
    if (tid == 0)
        lam_ws[m] = (float)dsig(pr[1060] + AWL[m] + SXL[t * 32 + b] + (double)b_l[0]);
}

__global__ void k_hTcT(float* out, const double* hdecF, const double* cdecF) {
    int i = blockIdx.x * 256 + threadIdx.x;
    if (i >= 16000) return;
    int b = i / 500, u = i - b * 500;
    out[OUT_HT + i] = (float)hdecF[u * 32 + b];
    out[OUT_CT + i] = (float)cdecF[u * 32 + b];
}

// ---------------- logits GEMM (f32 vector): d_out = outs @ W_lin^T + b_lin ----------------

__global__ __launch_bounds__(256) void k_gemm_logits_f32(const float* outs32, const float* W_lin,
                                                         const float* b_lin, float* d_out) {
    __shared__ float As[16][68], Bs[16][68];
    int n0 = blockIdx.x * 64, m0 = blockIdx.y * 64;
    int tid = threadIdx.x;
    int ty = tid >> 4, tx = tid & 15;
    int lr = tid >> 2, lc = tid & 3;
    float acc[4][4];
#pragma unroll
    for (int i = 0; i < 4; ++i)
#pragma unroll
        for (int j = 0; j < 4; ++j) acc[i][j] = 0.f;

    for (int k0 = 0; k0 < 512; k0 += 16) {
        int k4 = k0 + lc * 4;
        float4 av = *(const float4*)(outs32 + (size_t)(m0 + lr) * 512 + k4);
        int n = n0 + lr;
        float4 bv;
        if (n < VS && k4 < 500) bv = *(const float4*)(W_lin + (size_t)n * 500 + k4);
        else bv = make_float4(0.f, 0.f, 0.f, 0.f);
        __syncthreads();
        As[lc * 4 + 0][lr] = av.x; As[lc * 4 + 1][lr] = av.y;
        As[lc * 4 + 2][lr] = av.z; As[lc * 4 + 3][lr] = av.w;
        Bs[lc * 4 + 0][lr] = bv.x; Bs[lc * 4 + 1][lr] = bv.y;
        Bs[lc * 4 + 2][lr] = bv.z; Bs[lc * 4 + 3][lr] = bv.w;
        __syncthreads();
#pragma unroll
        for (int kk = 0; kk < 16; ++kk) {
            float4 a4 = *(const float4*)&As[kk][ty * 4];
            float4 b4 = *(const float4*)&Bs[kk][tx * 4];
            float ar[4] = {a4.x, a4.y, a4.z, a4.w};
            float br[4] = {b4.x, b4.y, b4.z, b4.w};
#pragma unroll
            for (int i = 0; i < 4; ++i)
#pragma unroll
                for (int j = 0; j < 4; ++j) acc[i][j] += ar[i] * br[j];
        }
    }
#pragma unroll
    for (int j = 0; j < 4; ++j) {
        int n = n0 + tx * 4 + j;
        if (n < VS) {
            float bl = b_lin[n];
#pragma unroll
            for (int i = 0; i < 4; ++i) {
                int mm = m0 + ty * 4 + i;
                d_out[(size_t)mm * VS + n] = acc[i][j] + bl;
            }
        }
    }
}

// ---------------- softmax passes ----------------

__global__ void k_red1(const float* d_out, float* LS1) {
    int m = blockIdx.x, tid = threadIdx.x;
    const float* row = d_out + (size_t)m * VS;
    __shared__ float red[256];
    float lm = -3e38f;
    for (int v = tid; v < VS; v += 256) lm = fmaxf(lm, row[v]);
    red[tid] = lm; __syncthreads();
    for (int o = 128; o > 0; o >>= 1) { if (tid < o) red[tid] = fmaxf(red[tid], red[tid + o]); __syncthreads(); }
    float m1 = red[0]; __syncthreads();
    float ls = 0.f;
    for (int v = tid; v < VS; v += 256) ls += expf(row[v] - m1);
    red[tid] = ls; __syncthreads();
    for (int o = 128; o > 0; o >>= 1) { if (tid < o) red[tid] += red[tid + o]; __syncthreads(); }
    if (tid == 0) LS1[m] = m1 + logf(red[0]);
}

__global__ __launch_bounds__(256) void k_plexmix(float* d_out, const float* attn_ws, const float* align_prob,
                                                 const float* lam_ws, const float* LS1) {
    int b = blockIdx.y, v0 = blockIdx.x * 64, tid = threadIdx.x;
    __shared__ float attn_s[50 * 100];
    __shared__ float al[100 * 64];
    for (int i = tid; i < 5000; i += 256) attn_s[i] = attn_ws[(size_t)b * 5000 + i];
    for (int i = tid; i < 6400; i += 256) {
        int l = i >> 6, j = i & 63;
        int v = v0 + j;
        al[i] = (v < VS) ? align_prob[((size_t)b * 100 + l) * VS + v] : 0.f;
    }
    __syncthreads();
    for (int idx = tid; idx < 50 * 64; idx += 256) {
        int t = idx >> 6, j = idx & 63;
        int v = v0 + j;
        if (v < VS) {
            float acc = 0.f;
            for (int l = 0; l < 100; ++l) acc += attn_s[t * 100 + l] * al[l * 64 + j];
            int m = b * T + t;
            size_t p = (size_t)m * VS + v;
            float lamv = lam_ws[m];
            d_out[p] = lamv * acc + (1.f - lamv) * (d_out[p] - LS1[m]);
        }
    }
}

__global__ void k_final2(float* d_out, const float* E_target) {
    int m = blockIdx.x, tid = threadIdx.x;
    float* row = d_out + (size_t)m * VS;
    __shared__ float sm[256], ss[256], sbv[256];
    __shared__ int sbi[256];
    float rm = -3e38f, rs = 0.f, bv = -3e38f; int bi = 0;
    for (int v = tid; v < VS; v += 256) {
        float xv = row[v];
        if (xv > bv) { bv = xv; bi = v; }
        if (xv > rm) { rs = rs * expf(rm - xv) + 1.f; rm = xv; }
        else rs += expf(xv - rm);
    }
    sm[tid] = rm; ss[tid] = rs; sbv[tid] = bv; sbi[tid] = bi;
    __syncthreads();
    for (int o = 128; o > 0; o >>= 1) {
        if (tid < o) {
            float m1 = sm[tid], m2 = sm[tid + o];
            float M = fmaxf(m1, m2);
            ss[tid] = ss[tid] * expf(m1 - M) + ss[tid + o] * expf(m2 - M);
            sm[tid] = M;
            if (sbv[tid + o] > sbv[tid] || (sbv[tid + o] == sbv[tid] && sbi[tid + o] < sbi[tid])) {
                sbv[tid] = sbv[tid + o]; sbi[tid] = sbi[tid + o];
            }
        }
        __syncthreads();
    }
    float ls2 = sm[0] + logf(ss[0]);
    int amax = sbi[0];
    for (int v = tid; v < VS; v += 256) row[v] -= ls2;
    for (int j = tid; j < 300; j += 256)
        d_out[OUT_DP + (size_t)m * 300 + j] = E_target[(size_t)amax * 300 + j];
}

__global__ void k_attnpred2(const int* widx, const float* E_target, float* d_out) {
    int i = blockIdx.x * 256 + threadIdx.x;
    if (i >= 1600 * 300) return;
    int m = i / 300, j = i - m * 300;
    d_out[OUT_AP + i] = E_target[(size_t)widx[m] * 300 + j];
}

// ---------------- launch ----------------

extern "C" void kernel_launch(void* const* d_in, const int* in_sizes, int n_in,
                              void* d_out_v, int out_size, void* d_ws, size_t ws_size,
                              hipStream_t stream) {
    const float* align_prob = (const float*)d_in[1];
    const float* E_sent     = (const float*)d_in[2];
    const float* E_field    = (const float*)d_in[3];
    const float* E_ppos     = (const float*)d_in[4];
    const float* E_pneg     = (const float*)d_in[5];
    const float* E_target   = (const float*)d_in[6];
    const float* enc_Wih_f  = (const float*)d_in[7];
    const float* enc_Whh_f  = (const float*)d_in[8];
    const float* enc_b_f    = (const float*)d_in[9];
    const float* enc_Wih_b  = (const float*)d_in[10];
    const float* enc_Whh_b  = (const float*)d_in[11];
    const float* enc_b_b    = (const float*)d_in[12];
    const float* dec_Wih    = (const float*)d_in[13];
    const float* dec_Whh    = (const float*)d_in[14];
    const float* dec_b      = (const float*)d_in[15];
    const float* W_d        = (const float*)d_in[16];
    const float* W_z        = (const float*)d_in[17];
    const float* W_out      = (const float*)d_in[18];
    const float* b_out      = (const float*)d_in[19];
    const float* w_l        = (const float*)d_in[20];
    const float* b_l        = (const float*)d_in[21];
    const float* W_lin      = (const float*)d_in[22];
    const float* b_lin      = (const float*)d_in[23];
    const int* sent  = (const int*)d_in[24];
    const int* value = (const int*)d_in[25];
    const int* field = (const int*)d_in[26];
    const int* ppos  = (const int*)d_in[27];
    const int* pneg  = (const int*)d_in[28];

    char* ws = (char*)d_ws;
    float*  x      = (float*)(ws + O_X);
    float*  sx     = (float*)(ws + O_SX);
    float*  WihfT  = (float*)(ws + O_WIHFT);
    float*  WihbT  = (float*)(ws + O_WIHBT);
    float*  WdecT  = (float*)(ws + O_WDECT);
    float*  w4enc  = (float*)(ws + O_W4ENC);
    float*  w4dec  = (float*)(ws + O_W4DEC);
    float*  Wcat   = (float*)(ws + O_WCAT);
    double* xwF    = (double*)(ws + O_XWF);
    double* xwB    = (double*)(ws + O_XWB);
    double* xwD    = (double*)(ws + O_XWD);
    double* eoB    = (double*)(ws + O_EOB);
    double* E2     = (double*)(ws + O_E2);
    double* PROJ   = (double*)(ws + O_PROJ);
    double* Hd     = (double*)(ws + O_HD);
    double* hGenc  = (double*)(ws + O_HGENC);
    double* hGdec  = (double*)(ws + O_HGDEC);
    double* hencF  = (double*)(ws + O_HENCF);
    double* cencF  = (double*)(ws + O_CENCF);
    double* cdec0  = (double*)(ws + O_CDEC0);
    double* hdecF  = (double*)(ws + O_HDECF);
    double* cdecF  = (double*)(ws + O_CDECF);
    double* AD     = (double*)(ws + O_AD);
    float*  attn_ws= (float*)(ws + O_ATTN);
    double* E_wl   = (double*)(ws + O_EWL);
    double* SXL    = (double*)(ws + O_SXL);
    double* AWL    = (double*)(ws + O_AWL);
    float*  lam_ws = (float*)(ws + O_LAM);
    float*  LS1    = (float*)(ws + O_LS1);
    int*    widx   = (int*)(ws + O_WIDX);
    int*    barE   = (int*)(ws + O_BAR);
    int*    barD   = (int*)(ws + O_BAR) + 64 * 16;
    float*  outs32 = (float*)(ws + O_OUTS);
    float* out = (float*)d_out_v;

    // ---- prep (parallel) ----
    k_embed_x<<<(B * L * INE + 255) / 256, 256, 0, stream>>>(E_sent, E_field, E_ppos, E_pneg,
                                                             value, field, ppos, pneg, x);
    k_embed_sent<<<(T * B * 400 + 255) / 256, 256, 0, stream>>>(E_sent, sent, sx);
    k_transpose<<<(460 * 1000 + 255) / 256, 256, 0, stream>>>(WihfT, enc_Wih_f, 460, 1000);
    k_transpose<<<(460 * 1000 + 255) / 256, 256, 0, stream>>>(WihbT, enc_Wih_b, 460, 1000);
    k_transpose<<<(400 * 2000 + 255) / 256, 256, 0, stream>>>(WdecT, dec_Wih, 400, 2000);
    k_pack4<<<(250 * 250 * 4 + 255) / 256, 256, 0, stream>>>(w4enc, enc_Whh_f, 250, 250);
    k_pack4<<<(250 * 250 * 4 + 255) / 256, 256, 0, stream>>>(w4enc + 250000, enc_Whh_b, 250, 250);
    k_pack4<<<(500 * 500 * 4 + 255) / 256, 256, 0, stream>>>(w4dec, dec_Whh, 500, 500);
    k_pack_wcat<<<(500 * OC + 255) / 256, 256, 0, stream>>>(Wcat, W_d, W_z, W_out, w_l);
    k_zerod<<<(16000 + 255) / 256, 256, 0, stream>>>(hGenc, 16000);   // enc h phase 0
    k_zeroi<<<8, 256, 0, stream>>>(barE, 2048);                        // both barrier slot arrays
    k_sxl<<<(1600 + 255) / 256, 256, 0, stream>>>(sx, w_l, SXL);
    {
        dim3 g1(100, 4); k_gemm_xw<<<g1, 256, 0, stream>>>(xwF, x, L * INE, INE, WihfT, enc_b_f, 460, 1000);
        dim3 g2(100, 4); k_gemm_xw<<<g2, 256, 0, stream>>>(xwB, x, L * INE, INE, WihbT, enc_b_b, 460, 1000);
        dim3 g3(50, 8);  k_gemm_xw<<<g3, 256, 0, stream>>>(xwD, sx, 400, B * 400, WdecT, dec_b, 400, 2000);
    }

    // ---- encoder: ONE kernel, LDS-staged h, coherent exchange, no fences ----
    k_enc_steps<<<NBE, 256, 0, stream>>>(xwF, xwB, w4enc, hGenc, eoB, hencF, cencF, barE);
    k_scramble<<<63, 256, 0, stream>>>(hGdec, cdec0, hencF, cencF);
    k_e2<<<3200, 256, 0, stream>>>(eoB, W_out, w_l, E2, E_wl);

    // ---- decoder cells: ONE kernel ----
    k_dec_steps<<<NBD, 256, 0, stream>>>(cdec0, xwD, w4dec, hGdec, Hd, hdecF, cdecF, barD);
    k_hTcT<<<63, 256, 0, stream>>>(out, hdecF, cdecF);

    // ---- attention: fully batched over all (t,b) ----
    k_proj_all<<<1600, 256, 0, stream>>>(Hd, Wcat, PROJ);
    k_attn_all<<<1600, 256, 0, stream>>>(PROJ, eoB, x, E_wl, value, attn_ws, AD, AWL, widx);
    k_outs<<<1600, 256, 0, stream>>>(PROJ, AD, E2, AWL, SXL, b_out, b_l, outs32, lam_ws);

    // ---- output head ----
    {
        dim3 gg(313, 25);
        k_gemm_logits_f32<<<gg, 256, 0, stream>>>(outs32, W_lin, b_lin, out);
    }
    k_red1<<<1600, 256, 0, stream>>>(out, LS1);
    {
        dim3 gp(313, 32);
        k_plexmix<<<gp, 256, 0, stream>>>(out, attn_ws, align_prob, lam_ws, LS1);
    }
    k_final2<<<1600, 256, 0, stream>>>(out, E_target);
    k_attnpred2<<<(1600 * 300 + 255) / 256, 256, 0, stream>>>(widx, E_target, out);
}

// Round 9
// 6129.921 us; speedup vs baseline: 1.4382x; 1.2312x over previous
//
#include <hip/hip_runtime.h>

#define DI __device__ __forceinline__

constexpr int B = 32, L = 100, T = 50;
constexpr int VS = 20000;
constexpr int HR = 250, HD = 500;
constexpr int INE = 460;
constexpr int OC = 1072;   // padded Wcat columns: 500 hwd | 60 hz | 500 hWo1 | 1 hwl | pad
constexpr int NBE = 64;    // encoder blocks (32 per direction)
constexpr int NBD = 63;    // decoder blocks

// ---- workspace byte offsets ----
constexpr size_t O_X      = 0;                      // x [B][L][460] f32
constexpr size_t O_SX     = 5888000;                // sent_x [T][B][400] f32
constexpr size_t O_WIHFT  = 8448000;                // enc_Wih_f^T [460][1000] f32
constexpr size_t O_WIHBT  = 10288000;
constexpr size_t O_WDECT  = 12128000;               // dec_Wih^T [400][2000] f32
constexpr size_t O_W4ENC  = 15328000;               // [2dir][250u][250k][4g] f32
constexpr size_t O_W4DEC  = 17328000;               // [500u][500k][4g] f32
constexpr size_t O_WCAT   = 21328000;               // [500][1072] f32
constexpr size_t O_XWF    = 23472000;               // [100][1000][32] f64
constexpr size_t O_XWB    = 49072000;
constexpr size_t O_XWD    = 74672000;               // [50][2000][32] f64
constexpr size_t O_EOB    = 100272000;              // enc_out [32][100][500] f64
constexpr size_t O_E2     = 113072000;              // [32][100][500] f64
constexpr size_t O_PROJ   = 125872000;              // [50][32][1072] f64
constexpr size_t O_HD     = 139593600;              // [1600][500] f64 (row t*32+b)
constexpr size_t O_HGENC  = 145993600;              // [2ph][16000] f64
constexpr size_t O_HGDEC  = 146249600;              // [2ph][16000] f64
constexpr size_t O_HENCF  = 146505600;              // [2dir][250][32] f64 final
constexpr size_t O_CENCF  = 146633600;
constexpr size_t O_CDEC0  = 146761600;              // [500][32] f64 scrambled c init
constexpr size_t O_HDECF  = 146889600;              // [500][32] f64 final
constexpr size_t O_CDECF  = 147017600;
constexpr size_t O_AD     = 147145600;              // a f64 [1600][100]
constexpr size_t O_ATTN   = 148425600;              // [32][50][100] f32
constexpr size_t O_EWL    = 149065600;              // [32][100] f64
constexpr size_t O_SXL    = 149091200;              // [1600] f64 (t*32+b)
constexpr size_t O_AWL    = 149104000;              // [1600] f64 (b*50+t)
constexpr size_t O_LAM    = 149116800;              // [1600] f32
constexpr size_t O_LS1    = 149123200;              // [1600] f32
constexpr size_t O_WIDX   = 149129600;              // [1600] int
constexpr size_t O_BAR    = 149136000;              // 2 x 64 slots x 16 ints (64B padded)
constexpr size_t O_OUTS   = 149144192;              // outs f32 [1600][512]
// end ~152.4 MB (<=158.4MB proven)

// output element offsets (f32)
constexpr size_t OUT_HT  = 32000000;
constexpr size_t OUT_CT  = 32016000;
constexpr size_t OUT_AP  = 32032000;
constexpr size_t OUT_DP  = 32512000;

DI double dsig(double x) { return 1.0 / (1.0 + exp(-x)); }

// coherent (cache-bypassing, agent-scope) load/store — the ONLY cross-block data path
DI double cld(const double* p) {
    return __hip_atomic_load(p, __ATOMIC_RELAXED, __HIP_MEMORY_SCOPE_AGENT);
}
DI void cst(double* p, double v) {
    __hip_atomic_store(p, v, __ATOMIC_RELAXED, __HIP_MEMORY_SCOPE_AGENT);
}

// batched coherent stage: issue 32 independent uncached loads into regs, then 32 LDS writes.
// One vmcnt drain per batch instead of per element (the R8 loop serialized ~31 x ~900ns).
DI void stage8000(double* hL, const double* hsrc, int tid) {
    double r[32];
#pragma unroll
    for (int j = 0; j < 32; ++j) {
        int idx = j * 256 + tid;
        r[j] = (idx < 8000) ? cld(&hsrc[idx]) : 0.0;
    }
#pragma unroll
    for (int j = 0; j < 32; ++j) {
        int idx = j * 256 + tid;
        if (idx < 8000) hL[idx] = r[j];
    }
}

// fence-free barrier: __syncthreads drains every wave's vmcnt (coherent stores then globally
// visible), signal own slot with a coherent store, wave0 lanes poll all slots coherently.
DI void gbar(int* slots, int target, int nb) {
    __syncthreads();                       // drains vmcnt/lgkmcnt for ALL waves (release)
    if (threadIdx.x == 0)
        __hip_atomic_store(&slots[blockIdx.x * 16], target,
                           __ATOMIC_RELAXED, __HIP_MEMORY_SCOPE_AGENT);
    if ((int)threadIdx.x < nb) {
        int spins = 0;
        while (__hip_atomic_load(&slots[threadIdx.x * 16], __ATOMIC_RELAXED,
                                 __HIP_MEMORY_SCOPE_AGENT) < target) {
            __builtin_amdgcn_s_sleep(1);      // back off: cut uncached-load flood
            if (++spins > 50000000) break;    // bounded: no hang on bug
        }
    }
    asm volatile("" ::: "memory");         // compiler barrier only — no HW invalidate
    __syncthreads();
}

// ---------------- prep kernels ----------------

__global__ void k_embed_x(const float* Es, const float* Ef, const float* Ep, const float* En,
                          const int* value, const int* field, const int* ppos, const int* pneg,
                          float* x) {
    int i = blockIdx.x * 256 + threadIdx.x;
    if (i >= B * L * INE) return;
    int j = i % INE, bl = i / INE;
    float v;
    if (j < 400)      v = Es[(size_t)value[bl] * 400 + j];
    else if (j < 450) v = Ef[(size_t)field[bl] * 50 + (j - 400)];
    else if (j < 455) v = Ep[(size_t)ppos[bl] * 5 + (j - 450)];
    else              v = En[(size_t)pneg[bl] * 5 + (j - 455)];
    x[i] = v;
}

__global__ void k_embed_sent(const float* Es, const int* sent, float* sx) {
    int i = blockIdx.x * 256 + threadIdx.x;
    if (i >= T * B * 400) return;
    int k = i % 400, tb = i / 400;
    int b = tb % B, t = tb / B;
    sx[i] = Es[(size_t)sent[b * T + t] * 400 + k];
}

__global__ void k_transpose(float* dst, const float* src, int K, int G) {
    int i = blockIdx.x * 256 + threadIdx.x;
    if (i >= K * G) return;
    int g = i % G, k = i / G;
    dst[i] = src[(size_t)g * K + k];
}

__global__ void k_pack4(float* dst, const float* src, int U, int Kh) {
    int i = blockIdx.x * 256 + threadIdx.x;
    if (i >= U * Kh * 4) return;
    int g = i & 3, rest = i >> 2;
    int k = rest % Kh, u = rest / Kh;
    dst[i] = src[((size_t)(g * U + u)) * Kh + k];
}

__global__ void k_pack_wcat(float* dst, const float* Wd, const float* Wz, const float* Wo, const float* wl) {
    int i = blockIdx.x * 256 + threadIdx.x;
    if (i >= 500 * OC) return;
    int o = i % OC, d = i / OC;
    float v = 0.f;
    if (o < 500)       v = Wd[(size_t)d * 500 + o];
    else if (o < 560)  v = Wz[(size_t)d * 60 + (o - 500)];
    else if (o < 1060) v = Wo[(size_t)d * 500 + (o - 560)];
    else if (o == 1060) v = wl[d];
    dst[i] = v;
}

__global__ void k_zerod(double* p, int n) {
    int i = blockIdx.x * 256 + threadIdx.x;
    if (i < n) p[i] = 0.0;
}

__global__ void k_zeroi(int* p, int n) {
    int i = blockIdx.x * 256 + threadIdx.x;
    if (i < n) p[i] = 0;
}

// out[t][g][b] = bias[g] + sum_k xs[b,t,k] * Wt[k][g]   (f64 accumulate)
__global__ __launch_bounds__(256) void k_gemm_xw(double* out, const float* xs, int bstride, int tstride,
                                                 const float* Wt, const float* bias, int K, int G) {
    __shared__ float xls[460 * 33];
    int t = blockIdx.x;
    int g = blockIdx.y * 256 + threadIdx.x;
    bool act = g < G;
    for (int i = threadIdx.x; i < 32 * K; i += 256) {
        int b = i / K, k = i - b * K;
        xls[k * 33 + b] = xs[(size_t)b * bstride + (size_t)t * tstride + k];
    }
    __syncthreads();
    double acc[32];
    double bs = act ? (double)bias[g] : 0.0;
#pragma unroll
    for (int b = 0; b < 32; ++b) acc[b] = bs;
    for (int k = 0; k < K; ++k) {
        double w = act ? (double)Wt[(size_t)k * G + g] : 0.0;
        const float* xr = &xls[k * 33];
#pragma unroll
        for (int b = 0; b < 32; ++b) acc[b] += w * (double)xr[b];
    }
    if (act) {
        double* op = out + ((size_t)t * G + g) * 32;
#pragma unroll
        for (int b = 0; b < 32; ++b) op[b] = acc[b];
    }
}

// ---------------- encoder: 64 blocks (32/dir), LDS-staged h, fence-free barrier ----------------

__global__ __launch_bounds__(256) void k_enc_steps(const double* xwF, const double* xwB,
                                                   const float* w4enc, double* hG,
                                                   double* eoB, double* hencF, double* cencF,
                                                   int* slots) {
    __shared__ double hL[8000];               // 64 KB: this direction's h vector
    int tid = threadIdx.x;
    int bid = blockIdx.x;
    int dir = bid >> 5;                       // blocks 0-31: dir0, 32-63: dir1
    int g = (bid & 31) * 256 + tid;           // [0,8192)
    bool act = g < 8000;
    int u = act ? (g >> 5) : 0;
    int b = act ? (g & 31) : 0;
    const double* xw = dir ? xwB : xwF;
    const float4* W4 = (const float4*)w4enc + (size_t)(dir * 250 + u) * 250;
    double c = 0.0;
    // hG phase 0 pre-zeroed by prep (normal stores, flushed at that kernel's end)
    for (int s = 0; s < L; ++s) {
        int ph = s & 1;
        stage8000(hL, hG + ph * 16000 + dir * 8000, tid);   // batched coherent stage
        __syncthreads();
        if (act) {
            int tin = dir ? (L - 1 - s) : s;
            double zi = xw[((size_t)tin * 1000 + 0 * HR + u) * 32 + b];
            double zf = xw[((size_t)tin * 1000 + 1 * HR + u) * 32 + b];
            double zg = xw[((size_t)tin * 1000 + 2 * HR + u) * 32 + b];
            double zo = xw[((size_t)tin * 1000 + 3 * HR + u) * 32 + b];
#pragma unroll 4
            for (int k = 0; k < 250; ++k) {
                double hv = hL[k * 32 + b];
                float4 w = W4[k];                 // cached — never invalidated
                zi += (double)w.x * hv; zf += (double)w.y * hv;
                zg += (double)w.z * hv; zo += (double)w.w * hv;
            }
            double cn = dsig(zf) * c + dsig(zi) * tanh(zg);
            double hn = dsig(zo) * tanh(cn);
            c = cn;
            cst(&hG[(ph ^ 1) * 16000 + dir * 8000 + u * 32 + b], hn);  // coherent publish
            eoB[((size_t)b * 100 + tin) * 500 + dir * 250 + u] = hn;   // normal (post-kernel reader)
            if (s == L - 1) {
                hencF[dir * 8000 + u * 32 + b] = hn;
                cencF[dir * 8000 + u * 32 + b] = cn;
            }
        }
        gbar(slots, s + 1, NBE);
    }
}

// replicate torch .view on [2,B,250] -> [B,500] ; write h0 directly into hG_dec phase 0
__global__ void k_scramble(double* hGdec, double* cdec0, const double* hencF, const double* cencF) {
    int gt = blockIdx.x * 256 + threadIdx.x;
    if (gt >= 16000) return;
    int bb = gt / 500, j = gt - bb * 500;
    int d = gt / 8000, rem = gt - d * 8000;
    int bs = rem / 250, us = rem - bs * 250;
    hGdec[j * 32 + bb] = hencF[d * 8000 + us * 32 + bs];
    cdec0[j * 32 + bb] = cencF[d * 8000 + us * 32 + bs];
}

// ---------------- attention precomputes ----------------

__global__ __launch_bounds__(256) void k_e2(const double* eoB, const float* Wo, const float* wl,
                                            double* E2, double* E_wl) {
    __shared__ double eo_s[500];
    int bid = blockIdx.x;              // [0,3200)
    int b = bid / 100, l = bid - b * 100;
    int tid = threadIdx.x;
    for (int j = tid; j < 500; j += 256) eo_s[j] = eoB[((size_t)b * 100 + l) * 500 + j];
    __syncthreads();
#pragma unroll 2
    for (int e = tid; e < 500; e += 256) {
        double acc = 0.0;
        for (int j = 0; j < 500; ++j)
            acc += eo_s[j] * (double)Wo[(size_t)(500 + j) * 500 + e];
        E2[((size_t)b * 100 + l) * 500 + e] = acc;
    }
    if (tid < 64) {
        double p = 0.0;
        for (int j = tid; j < 500; j += 64) p += eo_s[j] * (double)wl[500 + j];
        for (int off = 32; off > 0; off >>= 1) p += __shfl_down(p, off);
        if (tid == 0) E_wl[b * 100 + l] = p;
    }
}

__global__ void k_sxl(const float* sx, const float* wl, double* SXL) {
    int i = blockIdx.x * 256 + threadIdx.x;
    if (i >= 1600) return;
    double acc = 0.0;
    for (int k = 0; k < 400; ++k) acc += (double)sx[(size_t)i * 400 + k] * (double)wl[1000 + k];
    SXL[i] = acc;
}

// ---------------- decoder cells: 63 blocks, chunked LDS-staged h, fence-free barrier ----------------

__global__ __launch_bounds__(256) void k_dec_steps(const double* cdec0, const double* xwD,
                                                   const float* w4dec, double* hG,
                                                   double* Hd, double* hdecF, double* cdecF,
                                                   int* slots) {
    __shared__ double hL[8000];               // 64 KB: one k-half of h
    int tid = threadIdx.x;
    int gt = blockIdx.x * 256 + tid;
    bool act = gt < 16000;
    int u = act ? (gt >> 5) : 0;
    int b = act ? (gt & 31) : 0;
    const float4* W4 = (const float4*)w4dec + (size_t)u * 500;
    double c = act ? cdec0[u * 32 + b] : 0.0;
    // hG phase 0 filled by k_scramble (normal stores, flushed at kernel end)
    for (int t = 0; t < T; ++t) {
        int ph = t & 1;
        const double* hsrc = hG + ph * 16000;
        double zi = 0.0, zf = 0.0, zg = 0.0, zo = 0.0;
        if (act) {
            zi = xwD[((size_t)t * 2000 + 0 * HD + u) * 32 + b];
            zf = xwD[((size_t)t * 2000 + 1 * HD + u) * 32 + b];
            zg = xwD[((size_t)t * 2000 + 2 * HD + u) * 32 + b];
            zo = xwD[((size_t)t * 2000 + 3 * HD + u) * 32 + b];
        }
        // chunk 0: k in [0,250)
        stage8000(hL, hsrc, tid);
        __syncthreads();
        if (act) {
#pragma unroll 4
            for (int k = 0; k < 250; ++k) {
                double hv = hL[k * 32 + b];
                float4 w = W4[k];
                zi += (double)w.x * hv; zf += (double)w.y * hv;
                zg += (double)w.z * hv; zo += (double)w.w * hv;
            }
        }
        __syncthreads();
        // chunk 1: k in [250,500)
        stage8000(hL, hsrc + 8000, tid);
        __syncthreads();
        if (act) {
#pragma unroll 4
            for (int k = 0; k < 250; ++k) {
                double hv = hL[k * 32 + b];
                float4 w = W4[250 + k];
                zi += (double)w.x * hv; zf += (double)w.y * hv;
                zg += (double)w.z * hv; zo += (double)w.w * hv;
            }
            double cn = dsig(zf) * c + dsig(zi) * tanh(zg);
            double hn = dsig(zo) * tanh(cn);
            c = cn;
            cst(&hG[(ph ^ 1) * 16000 + u * 32 + b], hn);               // coherent publish
            Hd[((size_t)t * 32 + b) * 500 + u] = hn;                   // normal (post-kernel)
            if (t == T - 1) {
                hdecF[u * 32 + b] = hn;
                cdecF[u * 32 + b] = cn;
            }
        }
        gbar(slots, t + 1, NBD);
    }
}

// batched h-projections: PROJ[m2][o] = sum_d Hd[m2][d] * Wcat[d][o],  m2 = t*32+b
__global__ __launch_bounds__(256) void k_proj_all(const double* Hd, const float* Wcat, double* PROJ) {
    __shared__ double hrow[500];
    int m2 = blockIdx.x;               // [0,1600)
    int tid = threadIdx.x;
    for (int d = tid; d < 500; d += 256) hrow[d] = Hd[(size_t)m2 * 500 + d];
    __syncthreads();
    for (int o = tid; o < OC; o += 256) {
        double acc = 0.0;
        for (int d = 0; d < 500; ++d) acc += hrow[d] * (double)Wcat[(size_t)d * OC + o];
        PROJ[(size_t)m2 * OC + o] = acc;
    }
}

// batched scores + dual softmax + attn/AD/widx/awl : one block per (t,b)
__global__ __launch_bounds__(256) void k_attn_all(
        const double* PROJ, const double* eoB, const float* x, const double* E_wl, const int* value,
        float* attn_ws, double* AD, double* AWL, int* widx) {
    int bid = blockIdx.x;              // = t*32+b
    int t = bid >> 5, b = bid & 31;
    int tid = threadIdx.x;
    int m = b * T + t;
    __shared__ double hwd_s[500], hz_s[60], sd_s[100], sz_s[100], aL[100];
    __shared__ double red[256];
    __shared__ int ri[256];
    const double* pr = PROJ + (size_t)bid * OC;
    for (int k = tid; k < 500; k += 256) hwd_s[k] = pr[k];
    if (tid < 60) hz_s[tid] = pr[500 + tid];
    __syncthreads();
    int w = tid >> 6, lane = tid & 63;
    for (int l = w; l < 100; l += 4) {
        const double* er = eoB + ((size_t)b * 100 + l) * 500;
        double p = 0.0;
        for (int e = lane; e < 500; e += 64) p += hwd_s[e] * er[e];
        for (int off = 32; off > 0; off >>= 1) p += __shfl_down(p, off);
        if (lane == 0) sd_s[l] = p;
        const float* zr = x + ((size_t)b * 100 + l) * 460 + 400;
        double q = (lane < 60) ? hz_s[lane] * (double)zr[lane] : 0.0;
        for (int off = 32; off > 0; off >>= 1) q += __shfl_down(q, off);
        if (lane == 0) sz_s[l] = q;
    }
    __syncthreads();
    red[tid] = (tid < 100) ? sd_s[tid] : -1e300; __syncthreads();
    for (int o = 128; o > 0; o >>= 1) { if (tid < o) red[tid] = fmax(red[tid], red[tid + o]); __syncthreads(); }
    double md = red[0]; __syncthreads();
    red[tid] = (tid < 100) ? exp(sd_s[tid] - md) : 0.0; __syncthreads();
    for (int o = 128; o > 0; o >>= 1) { if (tid < o) red[tid] += red[tid + o]; __syncthreads(); }
    double Sd = red[0]; __syncthreads();
    red[tid] = (tid < 100) ? sz_s[tid] : -1e300; __syncthreads();
    for (int o = 128; o > 0; o >>= 1) { if (tid < o) red[tid] = fmax(red[tid], red[tid + o]); __syncthreads(); }
    double mz = red[0]; __syncthreads();
    red[tid] = (tid < 100) ? exp(sz_s[tid] - mz) : 0.0; __syncthreads();
    for (int o = 128; o > 0; o >>= 1) { if (tid < o) red[tid] += red[tid + o]; __syncthreads(); }
    double Sz = red[0]; __syncthreads();
    if (tid < 100) aL[tid] = (exp(sd_s[tid] - md) / Sd) * (exp(sz_s[tid] - mz) / Sz);
    __syncthreads();
    red[tid] = (tid < 100) ? aL[tid] : 0.0; __syncthreads();
    for (int o = 128; o > 0; o >>= 1) { if (tid < o) red[tid] += red[tid + o]; __syncthreads(); }
    double Sa = red[0]; __syncthreads();
    if (tid < 100) {
        double av = aL[tid] / (Sa + 1e-3);
        aL[tid] = av;
        attn_ws[(size_t)m * 100 + tid] = (float)av;
        AD[(size_t)m * 100 + tid] = av;
    }
    __syncthreads();
    red[tid] = (tid < 100) ? aL[tid] : -1e300;
    ri[tid]  = (tid < 100) ? tid : 0x7fffffff;
    __syncthreads();
    for (int o = 128; o > 0; o >>= 1) {
        if (tid < o) {
            if (red[tid + o] > red[tid] || (red[tid + o] == red[tid] && ri[tid + o] < ri[tid])) {
                red[tid] = red[tid + o]; ri[tid] = ri[tid + o];
            }
        }
        __syncthreads();
    }
    if (tid == 0) widx[m] = value[b * 100 + ri[0]];
    if (tid < 64) {
        double p = (tid < 100) ? aL[tid] * E_wl[b * 100 + tid] : 0.0;
        if (tid + 64 < 100) p += aL[tid + 64] * E_wl[b * 100 + tid + 64];
        for (int off = 32; off > 0; off >>= 1) p += __shfl_down(p, off);
        if (tid == 0) AWL[m] = p;
    }
}

// outs[m][e] = tanh(hWo1 + a@E2 + b_out); lam[m] = sigmoid(hwl + awl + sxl + b_l)
__global__ __launch_bounds__(256) void k_outs(const double* PROJ, const double* AD, const double* E2,
                                              const double* AWL, const double* SXL,
                                              const float* b_out, const float* b_l,
                                              float* outs32, float* lam_ws) {
    __shared__ double ad_s[100];
    int m = blockIdx.x, tid = threadIdx.x;
    int b = m / T, t = m - b * T;
    if (tid < 100) ad_s[tid] = AD[(size_t)m * 100 + tid];
    __syncthreads();
    const double* pr = PROJ + ((size_t)t * 32 + b) * OC;
#pragma unroll 2
    for (int e = tid; e < 512; e += 256) {
        if (e < 500) {
            double acc = pr[560 + e] + (double)b_out[e];
            const double* e2 = E2 + (size_t)b * 50000 + e;
            for (int l = 0; l < 100; ++l) acc += ad_s[l] * e2[l * 500];
            outs32[(size_t)m * 512 + e] = (float)tanh(acc);
        } else {
            outs32[(size_t)m * 512 + e] = 0.f;
        }
    }
    if (tid == 0)
        lam_ws[m] = (float)dsig(pr[1060] + AWL[m] + SXL[t * 32 + b] + (double)b_l[0]);
}

__global__ void k_hTcT(float* out, const double* hdecF, const double* cdecF) {
    int i = blockIdx.x * 256 + threadIdx.x;
    if (i >= 16000) return;
    int b = i / 500, u = i - b * 500;
    out[OUT_HT + i] = (float)hdecF[u * 32 + b];
    out[OUT_CT + i] = (float)cdecF[u * 32 + b];
}

// ---------------- logits GEMM (f32 vector): d_out = outs @ W_lin^T + b_lin ----------------

__global__ __launch_bounds__(256) void k_gemm_logits_f32(const float* outs32, const float* W_lin,
                                                         const float* b_lin, float* d_out) {
    __shared__ float As[16][68], Bs[16][68];
    int n0 = blockIdx.x * 64, m0 = blockIdx.y * 64;
    int tid = threadIdx.x;
    int ty = tid >> 4, tx = tid & 15;
    int lr = tid >> 2, lc = tid & 3;
    float acc[4][4];
#pragma unroll
    for (int i = 0; i < 4; ++i)
#pragma unroll
        for (int j = 0; j < 4; ++j) acc[i][j] = 0.f;

    for (int k0 = 0; k0 < 512; k0 += 16) {
        int k4 = k0 + lc * 4;
        float4 av = *(const float4*)(outs32 + (size_t)(m0 + lr) * 512 + k4);
        int n = n0 + lr;
        float4 bv;
        if (n < VS && k4 < 500) bv = *(const float4*)(W_lin + (size_t)n * 500 + k4);
        else bv = make_float4(0.f, 0.f, 0.f, 0.f);
        __syncthreads();
        As[lc * 4 + 0][lr] = av.x; As[lc * 4 + 1][lr] = av.y;
        As[lc * 4 + 2][lr] = av.z; As[lc * 4 + 3][lr] = av.w;
        Bs[lc * 4 + 0][lr] = bv.x; Bs[lc * 4 + 1][lr] = bv.y;
        Bs[lc * 4 + 2][lr] = bv.z; Bs[lc * 4 + 3][lr] = bv.w;
        __syncthreads();
#pragma unroll
        for (int kk = 0; kk < 16; ++kk) {
            float4 a4 = *(const float4*)&As[kk][ty * 4];
            float4 b4 = *(const float4*)&Bs[kk][tx * 4];
            float ar[4] = {a4.x, a4.y, a4.z, a4.w};
            float br[4] = {b4.x, b4.y, b4.z, b4.w};
#pragma unroll
            for (int i = 0; i < 4; ++i)
#pragma unroll
                for (int j = 0; j < 4; ++j) acc[i][j] += ar[i] * br[j];
        }
    }
#pragma unroll
    for (int j = 0; j < 4; ++j) {
        int n = n0 + tx * 4 + j;
        if (n < VS) {
            float bl = b_lin[n];
#pragma unroll
            for (int i = 0; i < 4; ++i) {
                int mm = m0 + ty * 4 + i;
                d_out[(size_t)mm * VS + n] = acc[i][j] + bl;
            }
        }
    }
}

// ---------------- softmax passes ----------------

__global__ void k_red1(const float* d_out, float* LS1) {
    int m = blockIdx.x, tid = threadIdx.x;
    const float* row = d_out + (size_t)m * VS;
    __shared__ float red[256];
    float lm = -3e38f;
    for (int v = tid; v < VS; v += 256) lm = fmaxf(lm, row[v]);
    red[tid] = lm; __syncthreads();
    for (int o = 128; o > 0; o >>= 1) { if (tid < o) red[tid] = fmaxf(red[tid], red[tid + o]); __syncthreads(); }
    float m1 = red[0]; __syncthreads();
    float ls = 0.f;
    for (int v = tid; v < VS; v += 256) ls += expf(row[v] - m1);
    red[tid] = ls; __syncthreads();
    for (int o = 128; o > 0; o >>= 1) { if (tid < o) red[tid] += red[tid + o]; __syncthreads(); }
    if (tid == 0) LS1[m] = m1 + logf(red[0]);
}

__global__ __launch_bounds__(256) void k_plexmix(float* d_out, const float* attn_ws, const float* align_prob,
                                                 const float* lam_ws, const float* LS1) {
    int b = blockIdx.y, v0 = blockIdx.x * 64, tid = threadIdx.x;
    __shared__ float attn_s[50 * 100];
    __shared__ float al[100 * 64];
    for (int i = tid; i < 5000; i += 256) attn_s[i] = attn_ws[(size_t)b * 5000 + i];
    for (int i = tid; i < 6400; i += 256) {
        int l = i >> 6, j = i & 63;
        int v = v0 + j;
        al[i] = (v < VS) ? align_prob[((size_t)b * 100 + l) * VS + v] : 0.f;
    }
    __syncthreads();
    for (int idx = tid; idx < 50 * 64; idx += 256) {
        int t = idx >> 6, j = idx & 63;
        int v = v0 + j;
        if (v < VS) {
            float acc = 0.f;
            for (int l = 0; l < 100; ++l) acc += attn_s[t * 100 + l] * al[l * 64 + j];
            int m = b * T + t;
            size_t p = (size_t)m * VS + v;
            float lamv = lam_ws[m];
            d_out[p] = lamv * acc + (1.f - lamv) * (d_out[p] - LS1[m]);
        }
    }
}

__global__ void k_final2(float* d_out, const float* E_target) {
    int m = blockIdx.x, tid = threadIdx.x;
    float* row = d_out + (size_t)m * VS;
    __shared__ float sm[256], ss[256], sbv[256];
    __shared__ int sbi[256];
    float rm = -3e38f, rs = 0.f, bv = -3e38f; int bi = 0;
    for (int v = tid; v < VS; v += 256) {
        float xv = row[v];
        if (xv > bv) { bv = xv; bi = v; }
        if (xv > rm) { rs = rs * expf(rm - xv) + 1.f; rm = xv; }
        else rs += expf(xv - rm);
    }
    sm[tid] = rm; ss[tid] = rs; sbv[tid] = bv; sbi[tid] = bi;
    __syncthreads();
    for (int o = 128; o > 0; o >>= 1) {
        if (tid < o) {
            float m1 = sm[tid], m2 = sm[tid + o];
            float M = fmaxf(m1, m2);
            ss[tid] = ss[tid] * expf(m1 - M) + ss[tid + o] * expf(m2 - M);
            sm[tid] = M;
            if (sbv[tid + o] > sbv[tid] || (sbv[tid + o] == sbv[tid] && sbi[tid + o] < sbi[tid])) {
                sbv[tid] = sbv[tid + o]; sbi[tid] = sbi[tid + o];
            }
        }
        __syncthreads();
    }
    float ls2 = sm[0] + logf(ss[0]);
    int amax = sbi[0];
    for (int v = tid; v < VS; v += 256) row[v] -= ls2;
    for (int j = tid; j < 300; j += 256)
        d_out[OUT_DP + (size_t)m * 300 + j] = E_target[(size_t)amax * 300 + j];
}

__global__ void k_attnpred2(const int* widx, const float* E_target, float* d_out) {
    int i = blockIdx.x * 256 + threadIdx.x;
    if (i >= 1600 * 300) return;
    int m = i / 300, j = i - m * 300;
    d_out[OUT_AP + i] = E_target[(size_t)widx[m] * 300 + j];
}

// ---------------- launch ----------------

extern "C" void kernel_launch(void* const* d_in, const int* in_sizes, int n_in,
                              void* d_out_v, int out_size, void* d_ws, size_t ws_size,
                              hipStream_t stream) {
    const float* align_prob = (const float*)d_in[1];
    const float* E_sent     = (const float*)d_in[2];
    const float* E_field    = (const float*)d_in[3];
    const float* E_ppos     = (const float*)d_in[4];
    const float* E_pneg     = (const float*)d_in[5];
    const float* E_target   = (const float*)d_in[6];
    const float* enc_Wih_f  = (const float*)d_in[7];
    const float* enc_Whh_f  = (const float*)d_in[8];
    const float* enc_b_f    = (const float*)d_in[9];
    const float* enc_Wih_b  = (const float*)d_in[10];
    const float* enc_Whh_b  = (const float*)d_in[11];
    const float* enc_b_b    = (const float*)d_in[12];
    const float* dec_Wih    = (const float*)d_in[13];
    const float* dec_Whh    = (const float*)d_in[14];
    const float* dec_b      = (const float*)d_in[15];
    const float* W_d        = (const float*)d_in[16];
    const float* W_z        = (const float*)d_in[17];
    const float* W_out      = (const float*)d_in[18];
    const float* b_out      = (const float*)d_in[19];
    const float* w_l        = (const float*)d_in[20];
    const float* b_l        = (const float*)d_in[21];
    const float* W_lin      = (const float*)d_in[22];
    const float* b_lin      = (const float*)d_in[23];
    const int* sent  = (const int*)d_in[24];
    const int* value = (const int*)d_in[25];
    const int* field = (const int*)d_in[26];
    const int* ppos  = (const int*)d_in[27];
    const int* pneg  = (const int*)d_in[28];

    char* ws = (char*)d_ws;
    float*  x      = (float*)(ws + O_X);
    float*  sx     = (float*)(ws + O_SX);
    float*  WihfT  = (float*)(ws + O_WIHFT);
    float*  WihbT  = (float*)(ws + O_WIHBT);
    float*  WdecT  = (float*)(ws + O_WDECT);
    float*  w4enc  = (float*)(ws + O_W4ENC);
    float*  w4dec  = (float*)(ws + O_W4DEC);
    float*  Wcat   = (float*)(ws + O_WCAT);
    double* xwF    = (double*)(ws + O_XWF);
    double* xwB    = (double*)(ws + O_XWB);
    double* xwD    = (double*)(ws + O_XWD);
    double* eoB    = (double*)(ws + O_EOB);
    double* E2     = (double*)(ws + O_E2);
    double* PROJ   = (double*)(ws + O_PROJ);
    double* Hd     = (double*)(ws + O_HD);
    double* hGenc  = (double*)(ws + O_HGENC);
    double* hGdec  = (double*)(ws + O_HGDEC);
    double* hencF  = (double*)(ws + O_HENCF);
    double* cencF  = (double*)(ws + O_CENCF);
    double* cdec0  = (double*)(ws + O_CDEC0);
    double* hdecF  = (double*)(ws + O_HDECF);
    double* cdecF  = (double*)(ws + O_CDECF);
    double* AD     = (double*)(ws + O_AD);
    float*  attn_ws= (float*)(ws + O_ATTN);
    double* E_wl   = (double*)(ws + O_EWL);
    double* SXL    = (double*)(ws + O_SXL);
    double* AWL    = (double*)(ws + O_AWL);
    float*  lam_ws = (float*)(ws + O_LAM);
    float*  LS1    = (float*)(ws + O_LS1);
    int*    widx   = (int*)(ws + O_WIDX);
    int*    barE   = (int*)(ws + O_BAR);
    int*    barD   = (int*)(ws + O_BAR) + 64 * 16;
    float*  outs32 = (float*)(ws + O_OUTS);
    float* out = (float*)d_out_v;

    // ---- prep (parallel) ----
    k_embed_x<<<(B * L * INE + 255) / 256, 256, 0, stream>>>(E_sent, E_field, E_ppos, E_pneg,
                                                             value, field, ppos, pneg, x);
    k_embed_sent<<<(T * B * 400 + 255) / 256, 256, 0, stream>>>(E_sent, sent, sx);
    k_transpose<<<(460 * 1000 + 255) / 256, 256, 0, stream>>>(WihfT, enc_Wih_f, 460, 1000);
    k_transpose<<<(460 * 1000 + 255) / 256, 256, 0, stream>>>(WihbT, enc_Wih_b, 460, 1000);
    k_transpose<<<(400 * 2000 + 255) / 256, 256, 0, stream>>>(WdecT, dec_Wih, 400, 2000);
    k_pack4<<<(250 * 250 * 4 + 255) / 256, 256, 0, stream>>>(w4enc, enc_Whh_f, 250, 250);
    k_pack4<<<(250 * 250 * 4 + 255) / 256, 256, 0, stream>>>(w4enc + 250000, enc_Whh_b, 250, 250);
    k_pack4<<<(500 * 500 * 4 + 255) / 256, 256, 0, stream>>>(w4dec, dec_Whh, 500, 500);
    k_pack_wcat<<<(500 * OC + 255) / 256, 256, 0, stream>>>(Wcat, W_d, W_z, W_out, w_l);
    k_zerod<<<(16000 + 255) / 256, 256, 0, stream>>>(hGenc, 16000);   // enc h phase 0
    k_zeroi<<<8, 256, 0, stream>>>(barE, 2048);                        // both barrier slot arrays
    k_sxl<<<(1600 + 255) / 256, 256, 0, stream>>>(sx, w_l, SXL);
    {
        dim3 g1(100, 4); k_gemm_xw<<<g1, 256, 0, stream>>>(xwF, x, L * INE, INE, WihfT, enc_b_f, 460, 1000);
        dim3 g2(100, 4); k_gemm_xw<<<g2, 256, 0, stream>>>(xwB, x, L * INE, INE, WihbT, enc_b_b, 460, 1000);
        dim3 g3(50, 8);  k_gemm_xw<<<g3, 256, 0, stream>>>(xwD, sx, 400, B * 400, WdecT, dec_b, 400, 2000);
    }

    // ---- encoder: ONE kernel, LDS-staged h, coherent exchange, no fences ----
    k_enc_steps<<<NBE, 256, 0, stream>>>(xwF, xwB, w4enc, hGenc, eoB, hencF, cencF, barE);
    k_scramble<<<63, 256, 0, stream>>>(hGdec, cdec0, hencF, cencF);
    k_e2<<<3200, 256, 0, stream>>>(eoB, W_out, w_l, E2, E_wl);

    // ---- decoder cells: ONE kernel ----
    k_dec_steps<<<NBD, 256, 0, stream>>>(cdec0, xwD, w4dec, hGdec, Hd, hdecF, cdecF, barD);
    k_hTcT<<<63, 256, 0, stream>>>(out, hdecF, cdecF);

    // ---- attention: fully batched over all (t,b) ----
    k_proj_all<<<1600, 256, 0, stream>>>(Hd, Wcat, PROJ);
    k_attn_all<<<1600, 256, 0, stream>>>(PROJ, eoB, x, E_wl, value, attn_ws, AD, AWL, widx);
    k_outs<<<1600, 256, 0, stream>>>(PROJ, AD, E2, AWL, SXL, b_out, b_l, outs32, lam_ws);

    // ---- output head ----
    {
        dim3 gg(313, 25);
        k_gemm_logits_f32<<<gg, 256, 0, stream>>>(outs32, W_lin, b_lin, out);
    }
    k_red1<<<1600, 256, 0, stream>>>(out, LS1);
    {
        dim3 gp(313, 32);
        k_plexmix<<<gp, 256, 0, stream>>>(out, attn_ws, align_prob, lam_ws, LS1);
    }
    k_final2<<<1600, 256, 0, stream>>>(out, E_target);
    k_attnpred2<<<(1600 * 300 + 255) / 256, 256, 0, stream>>>(widx, E_target, out);
}